// Round 5
// baseline (2267.744 us; speedup 1.0000x reference)
//
#include <hip/hip_runtime.h>
#include <math.h>

#define NN 25000
#define NE 400000

static constexpr float C_S_ = 0.3826834323650898f;   // sin(pi/8)
static constexpr float C_X_ = 0.9238795325112867f;   // cos(pi/8)
static constexpr float Q_   = 0.25f;                 // 1/sqrt(16)
static constexpr float Q_S3 = 0.25f * 0.5773502691896258f; // Q / sqrt(3)

__device__ inline unsigned short f2bf(float f) {
    union { float f; unsigned u; } v; v.f = f;
    unsigned r = v.u + 0x7fffu + ((v.u >> 16) & 1u);   // RNE
    return (unsigned short)(r >> 16);
}
__device__ inline float bf2f(unsigned short s) {
    union { unsigned u; float f; } v; v.u = ((unsigned)s) << 16;
    return v.f;
}

// ---------------- K0: pack all weights ----------------------------------------
// Wfc2T [192][100] f32; W4s [k=64][d=64] float4{sa,sc,1a,1c}; W4v [u=32][o=32] float4;
// W2s [k=96][d=96] float2{l2a,l2c}; W2v [u=96][o=96] float2.
__global__ void k_pack(const float* __restrict__ Wfc2, float* __restrict__ Wfc2T,
                       const float* __restrict__ Wsa, const float* __restrict__ Wsc,
                       const float* __restrict__ W1sa, const float* __restrict__ W1sc, float* __restrict__ W4s,
                       const float* __restrict__ Wva, const float* __restrict__ Wvc,
                       const float* __restrict__ W1va, const float* __restrict__ W1vc, float* __restrict__ W4v,
                       const float* __restrict__ Wl2sa, const float* __restrict__ Wl2sc, float* __restrict__ W2s,
                       const float* __restrict__ Wl2va, const float* __restrict__ Wl2vc, float* __restrict__ W2v)
{
    int t = blockIdx.x * blockDim.x + threadIdx.x;
    if (t < 19200) { int o = t / 100, j = t - o * 100; Wfc2T[o * 100 + j] = Wfc2[j * 192 + o]; return; }
    t -= 19200;
    if (t < 4096) {
        int k = t >> 6, d = t & 63;
        float4 v = make_float4(Wsa[k*64+d], Wsc[k*64+d], W1sa[k*64+d], W1sc[k*64+d]);
        ((float4*)W4s)[k*64+d] = v; return;
    }
    t -= 4096;
    if (t < 1024) {
        int u = t >> 5, o = t & 31;
        float4 v = make_float4(Wva[u*32+o], Wvc[u*32+o], W1va[u*32+o], W1vc[u*32+o]);
        ((float4*)W4v)[u*32+o] = v; return;
    }
    t -= 1024;
    if (t < 9216) {
        int k = t / 96, d = t - k * 96;
        float2 v = make_float2(Wl2sa[k*96+d], Wl2sc[k*96+d]);
        ((float2*)W2s)[k*96+d] = v; return;
    }
    t -= 9216;
    if (t < 9216) {
        int u = t / 96, o = t - u * 96;
        float2 v = make_float2(Wl2va[u*96+o], Wl2vc[u*96+o]);
        ((float2*)W2v)[u*96+o] = v; return;
    }
}

// ---------------- K1: node prep (packed weights) ------------------------------
__global__ __launch_bounds__(256) void k_node_prep(
    const float* __restrict__ ni, const float* __restrict__ attr, const float* __restrict__ cattr,
    const float* __restrict__ W4s, const float* __restrict__ W4v,
    float* __restrict__ x1, float* __restrict__ out)
{
    int t = blockIdx.x * blockDim.x + threadIdx.x;
    if (t >= NN * 160) return;
    int n = t / 160, d = t - n * 160;
    float a = attr[n], c = cattr[n];
    const float* row = ni + (size_t)n * 160;
    float ssa = 0.f, ssc = 0.f, s1a = 0.f, s1c = 0.f;
    if (d < 64) {
        const float4* W = (const float4*)W4s;
        #pragma unroll
        for (int k = 0; k < 64; ++k) {
            float x = row[k];
            float4 w = W[k * 64 + d];
            ssa += x * w.x; ssc += x * w.y; s1a += x * w.z; s1c += x * w.w;
        }
    } else {
        int idx = d - 64;
        int o = idx / 3, cc = idx - o * 3;
        const float4* W = (const float4*)W4v;
        #pragma unroll
        for (int u = 0; u < 32; ++u) {
            float x = row[64 + u * 3 + cc];
            float4 w = W[u * 32 + o];
            ssa += x * w.x; ssc += x * w.y; s1a += x * w.z; s1c += x * w.w;
        }
    }
    x1[t]  = a * s1a + c * s1c;
    out[t] = C_S_ * (a * ssa + c * ssc);
}

// ---------------- sort: histogram ---------------------------------------------
__global__ __launch_bounds__(256) void k_hist(const int* __restrict__ edst, int* __restrict__ cnt) {
    int e = blockIdx.x * blockDim.x + threadIdx.x;
    if (e >= NE) return;
    atomicAdd(&cnt[edst[e]], 1);
}

// ---------------- sort: single-block exclusive scan over NN counts ------------
__global__ __launch_bounds__(1024) void k_scan(const int* __restrict__ cnt,
                                               int* __restrict__ start, int* __restrict__ cursor) {
    __shared__ int wsum[16];
    __shared__ int carry_s;
    int lane = threadIdx.x & 63, wid = threadIdx.x >> 6;
    if (threadIdx.x == 0) carry_s = 0;
    __syncthreads();
    for (int base = 0; base < NN; base += 1024) {
        int i = base + threadIdx.x;
        int v = (i < NN) ? cnt[i] : 0;
        int x = v;
        #pragma unroll
        for (int off = 1; off < 64; off <<= 1) {
            int y = __shfl_up(x, off, 64);
            if (lane >= off) x += y;
        }
        if (lane == 63) wsum[wid] = x;
        __syncthreads();
        if (wid == 0 && lane < 16) {
            int s = wsum[lane];
            #pragma unroll
            for (int off = 1; off < 16; off <<= 1) {
                int y = __shfl_up(s, off, 64);
                if (lane >= off) s += y;
            }
            wsum[lane] = s;
        }
        __syncthreads();
        int woff = (wid > 0) ? wsum[wid - 1] : 0;
        int excl = x - v + woff + carry_s;
        if (i < NN) { start[i] = excl; cursor[i] = excl; }
        __syncthreads();
        if (threadIdx.x == 1023) carry_s += wsum[15];
        __syncthreads();
    }
    if (threadIdx.x == 0) start[NN] = NE;
}

// ---------------- sort: scatter edge ids --------------------------------------
__global__ __launch_bounds__(256) void k_scatter(const int* __restrict__ edst,
                                                 int* __restrict__ cursor,
                                                 int* __restrict__ sorted) {
    int e = blockIdx.x * blockDim.x + threadIdx.x;
    if (e >= NE) return;
    int p = atomicAdd(&cursor[edst[e]], 1);
    sorted[p] = e;
}

// ---------------- K2a: edge MLP -> 192 bf16 weights (edge order) --------------
// out col index == Wfc2T row index (w0|w1|w2|w3 concatenated).
// Col-groups of 8, one dwordx4 store per group -> tight line locality.
__global__ __launch_bounds__(256, 3) void k_edgew(
    const float* __restrict__ ele,
    const float* __restrict__ Wfc1, const float* __restrict__ Wfc2T,
    unsigned short* __restrict__ wbuf)
{
    int e = blockIdx.x * blockDim.x + threadIdx.x;
    if (e >= NE) return;

    float el[10];
    #pragma unroll
    for (int k = 0; k < 10; ++k) el[k] = ele[(size_t)e * 10 + k];

    float h[100];
    #pragma unroll
    for (int j = 0; j < 100; ++j) {
        float acc = 0.f;
        #pragma unroll
        for (int k = 0; k < 10; ++k) acc += el[k] * Wfc1[k * 100 + j];
        h[j] = acc / (1.f + __expf(-acc));
    }

    unsigned short* wrow = wbuf + (size_t)e * 192;

    for (int g = 0; g < 24; ++g) {            // rolled: compact code, uniform W addrs
        float acc[8];
        #pragma unroll
        for (int t = 0; t < 8; ++t) acc[t] = 0.f;
        const float* Wg = Wfc2T + (size_t)g * 8 * 100;
        #pragma unroll 2
        for (int j = 0; j < 100; ++j) {
            float hj = h[j];
            #pragma unroll
            for (int t = 0; t < 8; ++t) acc[t] += hj * Wg[t * 100 + j];
        }
        uint4 pk;
        pk.x = (unsigned)f2bf(acc[0]) | ((unsigned)f2bf(acc[1]) << 16);
        pk.y = (unsigned)f2bf(acc[2]) | ((unsigned)f2bf(acc[3]) << 16);
        pk.z = (unsigned)f2bf(acc[4]) | ((unsigned)f2bf(acc[5]) << 16);
        pk.w = (unsigned)f2bf(acc[6]) | ((unsigned)f2bf(acc[7]) << 16);
        *(uint4*)(wrow + g * 8) = pk;
    }
}

// ---------------- K2b: per-node gather + TP accumulate (no atomics) -----------
__global__ __launch_bounds__(384) void k_gather(
    const int* __restrict__ start, const int* __restrict__ sorted,
    const int* __restrict__ esrc, const float* __restrict__ eattr,
    const unsigned short* __restrict__ wbuf, const float* __restrict__ x1,
    float* __restrict__ agg)
{
    int n = blockIdx.x;
    int t = threadIdx.x;
    int s0 = start[n], s1 = start[n + 1];

    int widx, gidx, kind, csel = 0;
    float scale;
    if (t < 64)       { widx = t;                gidx = t;              kind = 0; scale = Q_;   }
    else if (t < 96)  { int o = t - 64;          widx = 160 + o; gidx = 64 + 3 * o; kind = 1; scale = Q_S3; }
    else if (t < 288) { int idx = t - 96; int u = idx / 3; csel = idx - 3 * u;
                        widx = 64 + u;           gidx = u;              kind = 2; scale = Q_;   }
    else              { int idx = t - 288; int o = idx / 3; int c = idx - 3 * o;
                        widx = 128 + o;          gidx = 64 + 3 * o + c; kind = 0; scale = Q_;   }

    float acc = 0.f;
    for (int i = s0; i < s1; ++i) {
        int e = sorted[i];
        int src = esrc[e];
        float4 ea = *(const float4*)(eattr + (size_t)e * 4);   // es, ev0, ev1, ev2
        const float* g = x1 + (size_t)src * 160;
        float wv = bf2f(wbuf[(size_t)e * 192 + widx]);
        float contrib;
        if (kind == 0)      contrib = wv * g[gidx] * ea.x;
        else if (kind == 1) contrib = wv * (g[gidx] * ea.y + g[gidx + 1] * ea.z + g[gidx + 2] * ea.w);
        else {
            float evc = (csel == 0) ? ea.y : ((csel == 1) ? ea.z : ea.w);
            contrib = wv * g[gidx] * evc;
        }
        acc += contrib;
    }
    agg[(size_t)n * 384 + t] = acc * scale;
}

// ---------------- fallback K2: fused edge + atomic scatter (known-good) -------
__global__ __launch_bounds__(256) void k_edge(
    const float* __restrict__ ele, const float* __restrict__ eattr,
    const int* __restrict__ esrc, const int* __restrict__ edst,
    const float* __restrict__ Wfc1, const float* __restrict__ Wfc2T,
    const float* __restrict__ x1, float* __restrict__ agg)
{
    int e = blockIdx.x * blockDim.x + threadIdx.x;
    if (e >= NE) return;
    float el[10];
    #pragma unroll
    for (int k = 0; k < 10; ++k) el[k] = ele[(size_t)e * 10 + k];
    float h[100];
    #pragma unroll
    for (int j = 0; j < 100; ++j) {
        float acc = 0.f;
        #pragma unroll
        for (int k = 0; k < 10; ++k) acc += el[k] * Wfc1[k * 100 + j];
        h[j] = acc / (1.f + __expf(-acc));
    }
    int src = esrc[e], dst = edst[e];
    float es  = eattr[(size_t)e * 4 + 0];
    float ev0 = eattr[(size_t)e * 4 + 1];
    float ev1 = eattr[(size_t)e * 4 + 2];
    float ev2 = eattr[(size_t)e * 4 + 3];
    const float* g  = x1 + (size_t)src * 160;
    float*       ag = agg + (size_t)dst * 384;
    for (int o = 0; o < 64; ++o) {
        float w0v = 0.f, w1v = 0.f;
        const float* c0 = Wfc2T + o * 100;
        const float* c1 = Wfc2T + (64 + o) * 100;
        #pragma unroll
        for (int j = 0; j < 100; ++j) { float hj = h[j]; w0v += hj * c0[j]; w1v += hj * c1[j]; }
        float gu = g[o];
        atomicAdd(&ag[o], w0v * gu * es * Q_);
        float b = w1v * gu * Q_;
        atomicAdd(&ag[96 + 3 * o + 0], b * ev0);
        atomicAdd(&ag[96 + 3 * o + 1], b * ev1);
        atomicAdd(&ag[96 + 3 * o + 2], b * ev2);
    }
    for (int o = 0; o < 32; ++o) {
        float w2v = 0.f, w3v = 0.f;
        const float* c2 = Wfc2T + (128 + o) * 100;
        const float* c3 = Wfc2T + (160 + o) * 100;
        #pragma unroll
        for (int j = 0; j < 100; ++j) { float hj = h[j]; w2v += hj * c2[j]; w3v += hj * c3[j]; }
        float g0 = g[64 + 3 * o + 0];
        float g1 = g[64 + 3 * o + 1];
        float g2 = g[64 + 3 * o + 2];
        float b = w2v * es * Q_;
        atomicAdd(&ag[288 + 3 * o + 0], b * g0);
        atomicAdd(&ag[288 + 3 * o + 1], b * g1);
        atomicAdd(&ag[288 + 3 * o + 2], b * g2);
        float dg = g0 * ev0 + g1 * ev1 + g2 * ev2;
        atomicAdd(&ag[64 + o], w3v * dg * Q_S3);
    }
}

// ---------------- K3a: l2 FCTP pair (packed weights) --------------------------
__global__ __launch_bounds__(256) void k_l2(
    const float* __restrict__ agg, const float* __restrict__ attr, const float* __restrict__ cattr,
    const float* __restrict__ W2s, const float* __restrict__ W2v,
    float* __restrict__ l2o)
{
    int t = blockIdx.x * blockDim.x + threadIdx.x;
    if (t >= NN * 384) return;
    int n = t / 384, d = t - n * 384;
    float a = attr[n], c = cattr[n];
    const float* m = agg + (size_t)n * 384;
    float va = 0.f, vc = 0.f;
    if (d < 96) {
        const float2* W = (const float2*)W2s;
        #pragma unroll 8
        for (int k = 0; k < 96; ++k) {
            float x = m[k];
            float2 w = W[k * 96 + d];
            va += x * w.x; vc += x * w.y;
        }
    } else {
        int idx = d - 96;
        int o = idx / 3, cc = idx - o * 3;
        const float2* W = (const float2*)W2v;
        #pragma unroll 8
        for (int u = 0; u < 96; ++u) {
            float x = m[96 + u * 3 + cc];
            float2 w = W[u * 96 + o];
            va += x * w.x; vc += x * w.y;
        }
    }
    l2o[t] = a * va + c * vc;
}

// ---------------- K3b: l3 FCTP + final combine --------------------------------
__global__ __launch_bounds__(256) void k_l3(
    const float* __restrict__ l2o, const float* __restrict__ sym,
    const float* __restrict__ Wl3s, const float* __restrict__ Wl3v,
    float* __restrict__ out)
{
    int t = blockIdx.x * blockDim.x + threadIdx.x;
    if (t >= NN * 160) return;
    int n = t / 160, d = t - n * 160;
    float s = sym[n];
    const float* m = l2o + (size_t)n * 384;
    float acc = 0.f;
    if (d < 64) {
        #pragma unroll 8
        for (int k = 0; k < 96; ++k) acc += m[k] * Wl3s[k * 64 + d];
    } else {
        int idx = d - 64;
        int o = idx / 3, cc = idx - o * 3;
        #pragma unroll 8
        for (int u = 0; u < 96; ++u) acc += m[96 + u * 3 + cc] * Wl3v[u * 32 + o];
    }
    out[t] = out[t] + C_X_ * s * acc;
}

extern "C" void kernel_launch(void* const* d_in, const int* in_sizes, int n_in,
                              void* d_out, int out_size, void* d_ws, size_t ws_size,
                              hipStream_t stream) {
    const float* ni    = (const float*)d_in[0];
    const float* attr  = (const float*)d_in[1];
    const float* cattr = (const float*)d_in[2];
    const float* sym   = (const float*)d_in[3];
    const float* eattr = (const float*)d_in[4];
    const float* ele   = (const float*)d_in[5];
    const int*   esrc  = (const int*)d_in[6];
    const int*   edst  = (const int*)d_in[7];
    const float* Ws_sc_a = (const float*)d_in[8];
    const float* Wv_sc_a = (const float*)d_in[9];
    const float* Ws_sc_c = (const float*)d_in[10];
    const float* Wv_sc_c = (const float*)d_in[11];
    const float* Ws_l1_a = (const float*)d_in[12];
    const float* Wv_l1_a = (const float*)d_in[13];
    const float* Ws_l1_c = (const float*)d_in[14];
    const float* Wv_l1_c = (const float*)d_in[15];
    const float* Wfc1    = (const float*)d_in[16];
    const float* Wfc2    = (const float*)d_in[17];
    const float* Ws_l2_a = (const float*)d_in[18];
    const float* Wv_l2_a = (const float*)d_in[19];
    const float* Ws_l2_c = (const float*)d_in[20];
    const float* Wv_l2_c = (const float*)d_in[21];
    const float* Ws_l3   = (const float*)d_in[22];
    const float* Wv_l3   = (const float*)d_in[23];

    float* out = (float*)d_out;
    float* ws  = (float*)d_ws;
    float* x1    = ws;                        // NN*160
    float* agg   = x1  + (size_t)NN * 160;    // NN*384
    float* l2o   = agg + (size_t)NN * 384;    // NN*384
    float* Wfc2T = l2o + (size_t)NN * 384;    // 19200
    float* W4s   = Wfc2T + 19200;             // 16384
    float* W4v   = W4s + 16384;               // 4096
    float* W2s   = W4v + 4096;                // 18432
    float* W2v   = W2s + 18432;               // 18432

    size_t base_floats = (size_t)NN * 160 + (size_t)NN * 384 * 2
                       + 19200 + 16384 + 4096 + 18432 + 18432;
    size_t need_base = base_floats * sizeof(float);
    if (ws_size < need_base) return;

    unsigned short* wbuf = (unsigned short*)(ws + base_floats);     // NE*192 bf16
    int* cnt    = (int*)(wbuf + (size_t)NE * 192);                  // NN
    int* start_ = cnt + NN;                                         // NN+1
    int* cursor = start_ + NN + 1;                                  // NN
    int* sorted = cursor + NN;                                      // NE
    size_t need_fast = need_base + (size_t)NE * 192 * 2
                     + ((size_t)NN * 3 + 1 + (size_t)NE) * sizeof(int);
    bool fast = (ws_size >= need_fast);

    k_pack<<<(42752 + 255) / 256, 256, 0, stream>>>(
        Wfc2, Wfc2T,
        Ws_sc_a, Ws_sc_c, Ws_l1_a, Ws_l1_c, W4s,
        Wv_sc_a, Wv_sc_c, Wv_l1_a, Wv_l1_c, W4v,
        Ws_l2_a, Ws_l2_c, W2s,
        Wv_l2_a, Wv_l2_c, W2v);

    k_node_prep<<<(NN * 160 + 255) / 256, 256, 0, stream>>>(
        ni, attr, cattr, W4s, W4v, x1, out);

    if (fast) {
        hipMemsetAsync(cnt, 0, (size_t)NN * sizeof(int), stream);
        k_hist<<<(NE + 255) / 256, 256, 0, stream>>>(edst, cnt);
        k_scan<<<1, 1024, 0, stream>>>(cnt, start_, cursor);
        k_scatter<<<(NE + 255) / 256, 256, 0, stream>>>(edst, cursor, sorted);
        k_edgew<<<(NE + 255) / 256, 256, 0, stream>>>(ele, Wfc1, Wfc2T, wbuf);
        k_gather<<<NN, 384, 0, stream>>>(start_, sorted, esrc, eattr, wbuf, x1, agg);
    } else {
        hipMemsetAsync(agg, 0, (size_t)NN * 384 * sizeof(float), stream);
        k_edge<<<(NE + 255) / 256, 256, 0, stream>>>(
            ele, eattr, esrc, edst, Wfc1, Wfc2T, x1, agg);
    }

    k_l2<<<(NN * 384 + 255) / 256, 256, 0, stream>>>(
        agg, attr, cattr, W2s, W2v, l2o);

    k_l3<<<(NN * 160 + 255) / 256, 256, 0, stream>>>(
        l2o, sym, Ws_l3, Wv_l3, out);
}

// Round 6
// 2156.212 us; speedup vs baseline: 1.0517x; 1.0517x over previous
//
#include <hip/hip_runtime.h>
#include <math.h>

#define NN 25000
#define NE 400000

static constexpr float C_S_ = 0.3826834323650898f;   // sin(pi/8)
static constexpr float C_X_ = 0.9238795325112867f;   // cos(pi/8)
static constexpr float Q_   = 0.25f;                 // 1/sqrt(16)
static constexpr float Q_S3 = 0.25f * 0.5773502691896258f; // Q / sqrt(3)

__device__ inline unsigned short f2bf(float f) {
    union { float f; unsigned u; } v; v.f = f;
    unsigned r = v.u + 0x7fffu + ((v.u >> 16) & 1u);   // RNE
    return (unsigned short)(r >> 16);
}
__device__ inline float bf2f(unsigned short s) {
    union { unsigned u; float f; } v; v.u = ((unsigned)s) << 16;
    return v.f;
}

// ---------------- K0: pack all weights ----------------------------------------
__global__ void k_pack(const float* __restrict__ Wfc2, float* __restrict__ Wfc2T,
                       const float* __restrict__ Wsa, const float* __restrict__ Wsc,
                       const float* __restrict__ W1sa, const float* __restrict__ W1sc, float* __restrict__ W4s,
                       const float* __restrict__ Wva, const float* __restrict__ Wvc,
                       const float* __restrict__ W1va, const float* __restrict__ W1vc, float* __restrict__ W4v,
                       const float* __restrict__ Wl2sa, const float* __restrict__ Wl2sc, float* __restrict__ W2s,
                       const float* __restrict__ Wl2va, const float* __restrict__ Wl2vc, float* __restrict__ W2v)
{
    int t = blockIdx.x * blockDim.x + threadIdx.x;
    if (t < 19200) { int o = t / 100, j = t - o * 100; Wfc2T[o * 100 + j] = Wfc2[j * 192 + o]; return; }
    t -= 19200;
    if (t < 4096) {
        int k = t >> 6, d = t & 63;
        float4 v = make_float4(Wsa[k*64+d], Wsc[k*64+d], W1sa[k*64+d], W1sc[k*64+d]);
        ((float4*)W4s)[k*64+d] = v; return;
    }
    t -= 4096;
    if (t < 1024) {
        int u = t >> 5, o = t & 31;
        float4 v = make_float4(Wva[u*32+o], Wvc[u*32+o], W1va[u*32+o], W1vc[u*32+o]);
        ((float4*)W4v)[u*32+o] = v; return;
    }
    t -= 1024;
    if (t < 9216) {
        int k = t / 96, d = t - k * 96;
        float2 v = make_float2(Wl2sa[k*96+d], Wl2sc[k*96+d]);
        ((float2*)W2s)[k*96+d] = v; return;
    }
    t -= 9216;
    if (t < 9216) {
        int u = t / 96, o = t - u * 96;
        float2 v = make_float2(Wl2va[u*96+o], Wl2vc[u*96+o]);
        ((float2*)W2v)[u*96+o] = v; return;
    }
}

// ---------------- K1: node prep (packed weights) ------------------------------
__global__ __launch_bounds__(256) void k_node_prep(
    const float* __restrict__ ni, const float* __restrict__ attr, const float* __restrict__ cattr,
    const float* __restrict__ W4s, const float* __restrict__ W4v,
    float* __restrict__ x1, float* __restrict__ out)
{
    int t = blockIdx.x * blockDim.x + threadIdx.x;
    if (t >= NN * 160) return;
    int n = t / 160, d = t - n * 160;
    float a = attr[n], c = cattr[n];
    const float* row = ni + (size_t)n * 160;
    float ssa = 0.f, ssc = 0.f, s1a = 0.f, s1c = 0.f;
    if (d < 64) {
        const float4* W = (const float4*)W4s;
        #pragma unroll
        for (int k = 0; k < 64; ++k) {
            float x = row[k];
            float4 w = W[k * 64 + d];
            ssa += x * w.x; ssc += x * w.y; s1a += x * w.z; s1c += x * w.w;
        }
    } else {
        int idx = d - 64;
        int o = idx / 3, cc = idx - o * 3;
        const float4* W = (const float4*)W4v;
        #pragma unroll
        for (int u = 0; u < 32; ++u) {
            float x = row[64 + u * 3 + cc];
            float4 w = W[u * 32 + o];
            ssa += x * w.x; ssc += x * w.y; s1a += x * w.z; s1c += x * w.w;
        }
    }
    x1[t]  = a * s1a + c * s1c;
    out[t] = C_S_ * (a * ssa + c * ssc);
}

// ---------------- sort: histogram ---------------------------------------------
__global__ __launch_bounds__(256) void k_hist(const int* __restrict__ edst, int* __restrict__ cnt) {
    int e = blockIdx.x * blockDim.x + threadIdx.x;
    if (e >= NE) return;
    atomicAdd(&cnt[edst[e]], 1);
}

// ---------------- sort: single-block exclusive scan over NN counts ------------
__global__ __launch_bounds__(1024) void k_scan(const int* __restrict__ cnt,
                                               int* __restrict__ start, int* __restrict__ cursor) {
    __shared__ int wsum[16];
    __shared__ int carry_s;
    int lane = threadIdx.x & 63, wid = threadIdx.x >> 6;
    if (threadIdx.x == 0) carry_s = 0;
    __syncthreads();
    for (int base = 0; base < NN; base += 1024) {
        int i = base + threadIdx.x;
        int v = (i < NN) ? cnt[i] : 0;
        int x = v;
        #pragma unroll
        for (int off = 1; off < 64; off <<= 1) {
            int y = __shfl_up(x, off, 64);
            if (lane >= off) x += y;
        }
        if (lane == 63) wsum[wid] = x;
        __syncthreads();
        if (wid == 0 && lane < 16) {
            int s = wsum[lane];
            #pragma unroll
            for (int off = 1; off < 16; off <<= 1) {
                int y = __shfl_up(s, off, 64);
                if (lane >= off) s += y;
            }
            wsum[lane] = s;
        }
        __syncthreads();
        int woff = (wid > 0) ? wsum[wid - 1] : 0;
        int excl = x - v + woff + carry_s;
        if (i < NN) { start[i] = excl; cursor[i] = excl; }
        __syncthreads();
        if (threadIdx.x == 1023) carry_s += wsum[15];
        __syncthreads();
    }
    if (threadIdx.x == 0) start[NN] = NE;
}

// ---------------- sort: scatter edge ids --------------------------------------
__global__ __launch_bounds__(256) void k_scatter(const int* __restrict__ edst,
                                                 int* __restrict__ cursor,
                                                 int* __restrict__ sorted) {
    int e = blockIdx.x * blockDim.x + threadIdx.x;
    if (e >= NE) return;
    int p = atomicAdd(&cursor[edst[e]], 1);
    sorted[p] = e;
}

// ---------------- K2a: edge MLP -> 192 bf16 weights (edge order) --------------
// h[100] MUST stay in VGPRs: j-loops fully unrolled (static indices), g-loop
// kept rolled (unroll 1) so code stays ~6.4KB, launch_bounds(256,2) gives the
// register budget (~130 needed). W addrs wave-uniform -> scalar loads from L2.
__global__ __launch_bounds__(256, 2) void k_edgew(
    const float* __restrict__ ele,
    const float* __restrict__ Wfc1, const float* __restrict__ Wfc2T,
    unsigned short* __restrict__ wbuf)
{
    int e = blockIdx.x * blockDim.x + threadIdx.x;
    if (e >= NE) return;

    float el[10];
    #pragma unroll
    for (int k = 0; k < 10; ++k) el[k] = ele[(size_t)e * 10 + k];

    float h[100];
    #pragma unroll
    for (int j = 0; j < 100; ++j) {
        float acc = 0.f;
        #pragma unroll
        for (int k = 0; k < 10; ++k) acc += el[k] * Wfc1[k * 100 + j];
        h[j] = acc / (1.f + __expf(-acc));
    }

    unsigned short* wrow = wbuf + (size_t)e * 192;

    #pragma unroll 1
    for (int g = 0; g < 24; ++g) {
        float a0 = 0.f, a1 = 0.f, a2 = 0.f, a3 = 0.f;
        float a4 = 0.f, a5 = 0.f, a6 = 0.f, a7 = 0.f;
        const float* Wg = Wfc2T + (size_t)g * 800;
        #pragma unroll
        for (int j = 0; j < 100; ++j) {
            float hj = h[j];
            a0 += hj * Wg[j];
            a1 += hj * Wg[100 + j];
            a2 += hj * Wg[200 + j];
            a3 += hj * Wg[300 + j];
            a4 += hj * Wg[400 + j];
            a5 += hj * Wg[500 + j];
            a6 += hj * Wg[600 + j];
            a7 += hj * Wg[700 + j];
        }
        uint4 pk;
        pk.x = (unsigned)f2bf(a0) | ((unsigned)f2bf(a1) << 16);
        pk.y = (unsigned)f2bf(a2) | ((unsigned)f2bf(a3) << 16);
        pk.z = (unsigned)f2bf(a4) | ((unsigned)f2bf(a5) << 16);
        pk.w = (unsigned)f2bf(a6) | ((unsigned)f2bf(a7) << 16);
        *(uint4*)(wrow + g * 8) = pk;
    }
}

// ---------------- K2b: per-node gather + TP accumulate (no atomics) -----------
__global__ __launch_bounds__(384) void k_gather(
    const int* __restrict__ start, const int* __restrict__ sorted,
    const int* __restrict__ esrc, const float* __restrict__ eattr,
    const unsigned short* __restrict__ wbuf, const float* __restrict__ x1,
    float* __restrict__ agg)
{
    int n = blockIdx.x;
    int t = threadIdx.x;
    int s0 = start[n], s1 = start[n + 1];

    int widx, gidx, kind, csel = 0;
    float scale;
    if (t < 64)       { widx = t;                gidx = t;              kind = 0; scale = Q_;   }
    else if (t < 96)  { int o = t - 64;          widx = 160 + o; gidx = 64 + 3 * o; kind = 1; scale = Q_S3; }
    else if (t < 288) { int idx = t - 96; int u = idx / 3; csel = idx - 3 * u;
                        widx = 64 + u;           gidx = u;              kind = 2; scale = Q_;   }
    else              { int idx = t - 288; int o = idx / 3; int c = idx - 3 * o;
                        widx = 128 + o;          gidx = 64 + 3 * o + c; kind = 0; scale = Q_;   }

    float acc = 0.f;
    for (int i = s0; i < s1; ++i) {
        int e = sorted[i];
        int src = esrc[e];
        float4 ea = *(const float4*)(eattr + (size_t)e * 4);   // es, ev0, ev1, ev2
        const float* g = x1 + (size_t)src * 160;
        float wv = bf2f(wbuf[(size_t)e * 192 + widx]);
        float contrib;
        if (kind == 0)      contrib = wv * g[gidx] * ea.x;
        else if (kind == 1) contrib = wv * (g[gidx] * ea.y + g[gidx + 1] * ea.z + g[gidx + 2] * ea.w);
        else {
            float evc = (csel == 0) ? ea.y : ((csel == 1) ? ea.z : ea.w);
            contrib = wv * g[gidx] * evc;
        }
        acc += contrib;
    }
    agg[(size_t)n * 384 + t] = acc * scale;
}

// ---------------- fallback K2: fused edge + atomic scatter (known-good) -------
__global__ __launch_bounds__(256) void k_edge(
    const float* __restrict__ ele, const float* __restrict__ eattr,
    const int* __restrict__ esrc, const int* __restrict__ edst,
    const float* __restrict__ Wfc1, const float* __restrict__ Wfc2T,
    const float* __restrict__ x1, float* __restrict__ agg)
{
    int e = blockIdx.x * blockDim.x + threadIdx.x;
    if (e >= NE) return;
    float el[10];
    #pragma unroll
    for (int k = 0; k < 10; ++k) el[k] = ele[(size_t)e * 10 + k];
    float h[100];
    #pragma unroll
    for (int j = 0; j < 100; ++j) {
        float acc = 0.f;
        #pragma unroll
        for (int k = 0; k < 10; ++k) acc += el[k] * Wfc1[k * 100 + j];
        h[j] = acc / (1.f + __expf(-acc));
    }
    int src = esrc[e], dst = edst[e];
    float es  = eattr[(size_t)e * 4 + 0];
    float ev0 = eattr[(size_t)e * 4 + 1];
    float ev1 = eattr[(size_t)e * 4 + 2];
    float ev2 = eattr[(size_t)e * 4 + 3];
    const float* g  = x1 + (size_t)src * 160;
    float*       ag = agg + (size_t)dst * 384;
    for (int o = 0; o < 64; ++o) {
        float w0v = 0.f, w1v = 0.f;
        const float* c0 = Wfc2T + o * 100;
        const float* c1 = Wfc2T + (64 + o) * 100;
        #pragma unroll
        for (int j = 0; j < 100; ++j) { float hj = h[j]; w0v += hj * c0[j]; w1v += hj * c1[j]; }
        float gu = g[o];
        atomicAdd(&ag[o], w0v * gu * es * Q_);
        float b = w1v * gu * Q_;
        atomicAdd(&ag[96 + 3 * o + 0], b * ev0);
        atomicAdd(&ag[96 + 3 * o + 1], b * ev1);
        atomicAdd(&ag[96 + 3 * o + 2], b * ev2);
    }
    for (int o = 0; o < 32; ++o) {
        float w2v = 0.f, w3v = 0.f;
        const float* c2 = Wfc2T + (128 + o) * 100;
        const float* c3 = Wfc2T + (160 + o) * 100;
        #pragma unroll
        for (int j = 0; j < 100; ++j) { float hj = h[j]; w2v += hj * c2[j]; w3v += hj * c3[j]; }
        float g0 = g[64 + 3 * o + 0];
        float g1 = g[64 + 3 * o + 1];
        float g2 = g[64 + 3 * o + 2];
        float b = w2v * es * Q_;
        atomicAdd(&ag[288 + 3 * o + 0], b * g0);
        atomicAdd(&ag[288 + 3 * o + 1], b * g1);
        atomicAdd(&ag[288 + 3 * o + 2], b * g2);
        float dg = g0 * ev0 + g1 * ev1 + g2 * ev2;
        atomicAdd(&ag[64 + o], w3v * dg * Q_S3);
    }
}

// ---------------- K3a: l2 FCTP pair (packed weights) --------------------------
__global__ __launch_bounds__(256) void k_l2(
    const float* __restrict__ agg, const float* __restrict__ attr, const float* __restrict__ cattr,
    const float* __restrict__ W2s, const float* __restrict__ W2v,
    float* __restrict__ l2o)
{
    int t = blockIdx.x * blockDim.x + threadIdx.x;
    if (t >= NN * 384) return;
    int n = t / 384, d = t - n * 384;
    float a = attr[n], c = cattr[n];
    const float* m = agg + (size_t)n * 384;
    float va = 0.f, vc = 0.f;
    if (d < 96) {
        const float2* W = (const float2*)W2s;
        #pragma unroll 8
        for (int k = 0; k < 96; ++k) {
            float x = m[k];
            float2 w = W[k * 96 + d];
            va += x * w.x; vc += x * w.y;
        }
    } else {
        int idx = d - 96;
        int o = idx / 3, cc = idx - o * 3;
        const float2* W = (const float2*)W2v;
        #pragma unroll 8
        for (int u = 0; u < 96; ++u) {
            float x = m[96 + u * 3 + cc];
            float2 w = W[u * 96 + o];
            va += x * w.x; vc += x * w.y;
        }
    }
    l2o[t] = a * va + c * vc;
}

// ---------------- K3b: l3 FCTP + final combine --------------------------------
__global__ __launch_bounds__(256) void k_l3(
    const float* __restrict__ l2o, const float* __restrict__ sym,
    const float* __restrict__ Wl3s, const float* __restrict__ Wl3v,
    float* __restrict__ out)
{
    int t = blockIdx.x * blockDim.x + threadIdx.x;
    if (t >= NN * 160) return;
    int n = t / 160, d = t - n * 160;
    float s = sym[n];
    const float* m = l2o + (size_t)n * 384;
    float acc = 0.f;
    if (d < 64) {
        #pragma unroll 8
        for (int k = 0; k < 96; ++k) acc += m[k] * Wl3s[k * 64 + d];
    } else {
        int idx = d - 64;
        int o = idx / 3, cc = idx - o * 3;
        #pragma unroll 8
        for (int u = 0; u < 96; ++u) acc += m[96 + u * 3 + cc] * Wl3v[u * 32 + o];
    }
    out[t] = out[t] + C_X_ * s * acc;
}

extern "C" void kernel_launch(void* const* d_in, const int* in_sizes, int n_in,
                              void* d_out, int out_size, void* d_ws, size_t ws_size,
                              hipStream_t stream) {
    const float* ni    = (const float*)d_in[0];
    const float* attr  = (const float*)d_in[1];
    const float* cattr = (const float*)d_in[2];
    const float* sym   = (const float*)d_in[3];
    const float* eattr = (const float*)d_in[4];
    const float* ele   = (const float*)d_in[5];
    const int*   esrc  = (const int*)d_in[6];
    const int*   edst  = (const int*)d_in[7];
    const float* Ws_sc_a = (const float*)d_in[8];
    const float* Wv_sc_a = (const float*)d_in[9];
    const float* Ws_sc_c = (const float*)d_in[10];
    const float* Wv_sc_c = (const float*)d_in[11];
    const float* Ws_l1_a = (const float*)d_in[12];
    const float* Wv_l1_a = (const float*)d_in[13];
    const float* Ws_l1_c = (const float*)d_in[14];
    const float* Wv_l1_c = (const float*)d_in[15];
    const float* Wfc1    = (const float*)d_in[16];
    const float* Wfc2    = (const float*)d_in[17];
    const float* Ws_l2_a = (const float*)d_in[18];
    const float* Wv_l2_a = (const float*)d_in[19];
    const float* Ws_l2_c = (const float*)d_in[20];
    const float* Wv_l2_c = (const float*)d_in[21];
    const float* Ws_l3   = (const float*)d_in[22];
    const float* Wv_l3   = (const float*)d_in[23];

    float* out = (float*)d_out;
    float* ws  = (float*)d_ws;
    float* x1    = ws;                        // NN*160
    float* agg   = x1  + (size_t)NN * 160;    // NN*384
    float* l2o   = agg + (size_t)NN * 384;    // NN*384
    float* Wfc2T = l2o + (size_t)NN * 384;    // 19200
    float* W4s   = Wfc2T + 19200;             // 16384
    float* W4v   = W4s + 16384;               // 4096
    float* W2s   = W4v + 4096;                // 18432
    float* W2v   = W2s + 18432;               // 18432

    size_t base_floats = (size_t)NN * 160 + (size_t)NN * 384 * 2
                       + 19200 + 16384 + 4096 + 18432 + 18432;
    size_t need_base = base_floats * sizeof(float);
    if (ws_size < need_base) return;

    unsigned short* wbuf = (unsigned short*)(ws + base_floats);     // NE*192 bf16
    int* cnt    = (int*)(wbuf + (size_t)NE * 192);                  // NN
    int* start_ = cnt + NN;                                         // NN+1
    int* cursor = start_ + NN + 1;                                  // NN
    int* sorted = cursor + NN;                                      // NE
    size_t need_fast = need_base + (size_t)NE * 192 * 2
                     + ((size_t)NN * 3 + 1 + (size_t)NE) * sizeof(int);
    bool fast = (ws_size >= need_fast);

    k_pack<<<(42752 + 255) / 256, 256, 0, stream>>>(
        Wfc2, Wfc2T,
        Ws_sc_a, Ws_sc_c, Ws_l1_a, Ws_l1_c, W4s,
        Wv_sc_a, Wv_sc_c, Wv_l1_a, Wv_l1_c, W4v,
        Ws_l2_a, Ws_l2_c, W2s,
        Wv_l2_a, Wv_l2_c, W2v);

    k_node_prep<<<(NN * 160 + 255) / 256, 256, 0, stream>>>(
        ni, attr, cattr, W4s, W4v, x1, out);

    if (fast) {
        hipMemsetAsync(cnt, 0, (size_t)NN * sizeof(int), stream);
        k_hist<<<(NE + 255) / 256, 256, 0, stream>>>(edst, cnt);
        k_scan<<<1, 1024, 0, stream>>>(cnt, start_, cursor);
        k_scatter<<<(NE + 255) / 256, 256, 0, stream>>>(edst, cursor, sorted);
        k_edgew<<<(NE + 255) / 256, 256, 0, stream>>>(ele, Wfc1, Wfc2T, wbuf);
        k_gather<<<NN, 384, 0, stream>>>(start_, sorted, esrc, eattr, wbuf, x1, agg);
    } else {
        hipMemsetAsync(agg, 0, (size_t)NN * 384 * sizeof(float), stream);
        k_edge<<<(NE + 255) / 256, 256, 0, stream>>>(
            ele, eattr, esrc, edst, Wfc1, Wfc2T, x1, agg);
    }

    k_l2<<<(NN * 384 + 255) / 256, 256, 0, stream>>>(
        agg, attr, cattr, W2s, W2v, l2o);

    k_l3<<<(NN * 160 + 255) / 256, 256, 0, stream>>>(
        l2o, sym, Ws_l3, Wv_l3, out);
}

// Round 7
// 1346.043 us; speedup vs baseline: 1.6847x; 1.6019x over previous
//
#include <hip/hip_runtime.h>
#include <math.h>

#define NN 25000
#define NE 400000

static constexpr float C_S_ = 0.3826834323650898f;   // sin(pi/8)
static constexpr float C_X_ = 0.9238795325112867f;   // cos(pi/8)
static constexpr float Q_   = 0.25f;                 // 1/sqrt(16)
static constexpr float Q_S3 = 0.25f * 0.5773502691896258f; // Q / sqrt(3)

typedef __attribute__((ext_vector_type(8))) short bf16x8;
typedef __attribute__((ext_vector_type(4))) float f32x4;

__device__ inline unsigned short f2bf(float f) {
    union { float f; unsigned u; } v; v.f = f;
    unsigned r = v.u + 0x7fffu + ((v.u >> 16) & 1u);   // RNE
    return (unsigned short)(r >> 16);
}
__device__ inline float bf2f(unsigned short s) {
    union { unsigned u; float f; } v; v.u = ((unsigned)s) << 16;
    return v.f;
}

// ---------------- K0: pack all weights ----------------------------------------
// Wfc2T [192][100] f32 (fallback path); W4s/W4v float4 packs; W2s/W2v float2 packs;
// Wfragb: bf16 MFMA B-fragments of Wfc2: [nt<12][ks<4][lane<64][i<8],
//   element = Wfc2[k*192+n], k = ks*32+(lane>>4)*8+i (0 if k>=100), n = nt*16+(lane&15).
__global__ void k_pack(const float* __restrict__ Wfc2, float* __restrict__ Wfc2T,
                       const float* __restrict__ Wsa, const float* __restrict__ Wsc,
                       const float* __restrict__ W1sa, const float* __restrict__ W1sc, float* __restrict__ W4s,
                       const float* __restrict__ Wva, const float* __restrict__ Wvc,
                       const float* __restrict__ W1va, const float* __restrict__ W1vc, float* __restrict__ W4v,
                       const float* __restrict__ Wl2sa, const float* __restrict__ Wl2sc, float* __restrict__ W2s,
                       const float* __restrict__ Wl2va, const float* __restrict__ Wl2vc, float* __restrict__ W2v,
                       unsigned short* __restrict__ Wfragb)
{
    int t = blockIdx.x * blockDim.x + threadIdx.x;
    if (t < 19200) { int o = t / 100, j = t - o * 100; Wfc2T[o * 100 + j] = Wfc2[j * 192 + o]; return; }
    t -= 19200;
    if (t < 4096) {
        int k = t >> 6, d = t & 63;
        float4 v = make_float4(Wsa[k*64+d], Wsc[k*64+d], W1sa[k*64+d], W1sc[k*64+d]);
        ((float4*)W4s)[k*64+d] = v; return;
    }
    t -= 4096;
    if (t < 1024) {
        int u = t >> 5, o = t & 31;
        float4 v = make_float4(Wva[u*32+o], Wvc[u*32+o], W1va[u*32+o], W1vc[u*32+o]);
        ((float4*)W4v)[u*32+o] = v; return;
    }
    t -= 1024;
    if (t < 9216) {
        int k = t / 96, d = t - k * 96;
        float2 v = make_float2(Wl2sa[k*96+d], Wl2sc[k*96+d]);
        ((float2*)W2s)[k*96+d] = v; return;
    }
    t -= 9216;
    if (t < 9216) {
        int u = t / 96, o = t - u * 96;
        float2 v = make_float2(Wl2va[u*96+o], Wl2vc[u*96+o]);
        ((float2*)W2v)[u*96+o] = v; return;
    }
    t -= 9216;
    if (t < 24576) {
        int i  = t & 7;
        int l  = (t >> 3) & 63;
        int ks = (t >> 9) & 3;
        int nt = t >> 11;
        int k = ks * 32 + ((l >> 4) << 3) + i;
        int n = nt * 16 + (l & 15);
        Wfragb[t] = (k < 100) ? f2bf(Wfc2[k * 192 + n]) : (unsigned short)0;
        return;
    }
}

// ---------------- K1: node prep (packed weights) ------------------------------
__global__ __launch_bounds__(256) void k_node_prep(
    const float* __restrict__ ni, const float* __restrict__ attr, const float* __restrict__ cattr,
    const float* __restrict__ W4s, const float* __restrict__ W4v,
    float* __restrict__ x1, float* __restrict__ out)
{
    int t = blockIdx.x * blockDim.x + threadIdx.x;
    if (t >= NN * 160) return;
    int n = t / 160, d = t - n * 160;
    float a = attr[n], c = cattr[n];
    const float* row = ni + (size_t)n * 160;
    float ssa = 0.f, ssc = 0.f, s1a = 0.f, s1c = 0.f;
    if (d < 64) {
        const float4* W = (const float4*)W4s;
        #pragma unroll
        for (int k = 0; k < 64; ++k) {
            float x = row[k];
            float4 w = W[k * 64 + d];
            ssa += x * w.x; ssc += x * w.y; s1a += x * w.z; s1c += x * w.w;
        }
    } else {
        int idx = d - 64;
        int o = idx / 3, cc = idx - o * 3;
        const float4* W = (const float4*)W4v;
        #pragma unroll
        for (int u = 0; u < 32; ++u) {
            float x = row[64 + u * 3 + cc];
            float4 w = W[u * 32 + o];
            ssa += x * w.x; ssc += x * w.y; s1a += x * w.z; s1c += x * w.w;
        }
    }
    x1[t]  = a * s1a + c * s1c;
    out[t] = C_S_ * (a * ssa + c * ssc);
}

// ---------------- sort: histogram ---------------------------------------------
__global__ __launch_bounds__(256) void k_hist(const int* __restrict__ edst, int* __restrict__ cnt) {
    int e = blockIdx.x * blockDim.x + threadIdx.x;
    if (e >= NE) return;
    atomicAdd(&cnt[edst[e]], 1);
}

// ---------------- sort: single-block exclusive scan over NN counts ------------
__global__ __launch_bounds__(1024) void k_scan(const int* __restrict__ cnt,
                                               int* __restrict__ start, int* __restrict__ cursor) {
    __shared__ int wsum[16];
    __shared__ int carry_s;
    int lane = threadIdx.x & 63, wid = threadIdx.x >> 6;
    if (threadIdx.x == 0) carry_s = 0;
    __syncthreads();
    for (int base = 0; base < NN; base += 1024) {
        int i = base + threadIdx.x;
        int v = (i < NN) ? cnt[i] : 0;
        int x = v;
        #pragma unroll
        for (int off = 1; off < 64; off <<= 1) {
            int y = __shfl_up(x, off, 64);
            if (lane >= off) x += y;
        }
        if (lane == 63) wsum[wid] = x;
        __syncthreads();
        if (wid == 0 && lane < 16) {
            int s = wsum[lane];
            #pragma unroll
            for (int off = 1; off < 16; off <<= 1) {
                int y = __shfl_up(s, off, 64);
                if (lane >= off) s += y;
            }
            wsum[lane] = s;
        }
        __syncthreads();
        int woff = (wid > 0) ? wsum[wid - 1] : 0;
        int excl = x - v + woff + carry_s;
        if (i < NN) { start[i] = excl; cursor[i] = excl; }
        __syncthreads();
        if (threadIdx.x == 1023) carry_s += wsum[15];
        __syncthreads();
    }
    if (threadIdx.x == 0) start[NN] = NE;
}

// ---------------- sort: scatter edge ids --------------------------------------
__global__ __launch_bounds__(256) void k_scatter(const int* __restrict__ edst,
                                                 int* __restrict__ cursor,
                                                 int* __restrict__ sorted) {
    int e = blockIdx.x * blockDim.x + threadIdx.x;
    if (e >= NE) return;
    int p = atomicAdd(&cursor[edst[e]], 1);
    sorted[p] = e;
}

// ---------------- K2a: MFMA edge-weight GEMM ----------------------------------
// Block = 256 thr (4 waves) = 64 edges. h[64][100] computed on VALU, stored bf16
// into XOR-swizzled LDS tile A[64][128]; W held as register B-fragments;
// 48x mfma_f32_16x16x32_bf16 per wave; epilogue bf16 stores to wbuf (edge order).
__global__ __launch_bounds__(256, 2) void k_edgew_mfma(
    const float* __restrict__ ele,
    const float* __restrict__ Wfc1, const unsigned short* __restrict__ Wfragb,
    unsigned short* __restrict__ wbuf)
{
    __shared__ float ele_s[640];
    __shared__ char  hA[64 * 256];      // [row=edge][128 bf16], byte ^= (row&7)<<4

    int tid  = threadIdx.x;
    int lane = tid & 63;
    int w    = tid >> 6;
    int e0   = blockIdx.x * 64;

    // phase 1: stage el [64][10]
    for (int idx = tid; idx < 640; idx += 256)
        ele_s[idx] = ele[(size_t)e0 * 10 + idx];
    __syncthreads();

    // phase 2: h = silu(el @ Wfc1); j is wave-uniform -> scalar Wfc1 loads
    #pragma unroll 1
    for (int it = 0; it < 25; ++it) {
        int t2 = tid + it * 256;
        int e_loc = t2 & 63;
        int j = t2 >> 6;
        const float* elp = ele_s + e_loc * 10;
        float acc = 0.f;
        #pragma unroll
        for (int k = 0; k < 10; ++k) acc += elp[k] * Wfc1[k * 100 + j];
        float hv = acc / (1.f + __expf(-acc));
        int col2 = j * 2;
        *(unsigned short*)(hA + e_loc * 256 + (col2 ^ ((e_loc & 7) << 4))) = f2bf(hv);
    }
    // zero-pad K 100..127 (bf16 cols 100..127 -> bytes 200..255)
    {
        int e_loc = tid & 63;
        int ci = tid >> 6;           // 0..3 -> 2 cols each
        #pragma unroll
        for (int q = 0; q < 2; ++q) {
            int col2 = 200 + (ci * 2 + q) * 14;   // 200,228; 214,242; ... hmm keep simple below
        }
    }
    // simple pad: 64 edges x 28 cols = 1792 shorts / 256 threads = 7 each
    for (int idx = tid; idx < 64 * 28; idx += 256) {
        int e_loc = idx / 28;
        int col2 = (100 + (idx - e_loc * 28)) * 2;
        *(unsigned short*)(hA + e_loc * 256 + (col2 ^ ((e_loc & 7) << 4))) = 0;
    }
    __syncthreads();

    // phase 3: B-frags (registers) + MFMA
    const bf16x8* Wv = (const bf16x8*)Wfragb;
    bf16x8 bfr[3][4];
    #pragma unroll
    for (int nt2 = 0; nt2 < 3; ++nt2)
        #pragma unroll
        for (int ks = 0; ks < 4; ++ks)
            bfr[nt2][ks] = Wv[(((w * 3 + nt2) * 4) + ks) * 64 + lane];

    f32x4 acc[4][3];
    #pragma unroll
    for (int mt = 0; mt < 4; ++mt)
        #pragma unroll
        for (int nt2 = 0; nt2 < 3; ++nt2)
            acc[mt][nt2] = (f32x4)0.f;

    #pragma unroll
    for (int mt = 0; mt < 4; ++mt) {
        int row = mt * 16 + (lane & 15);
        #pragma unroll
        for (int ks = 0; ks < 4; ++ks) {
            int kb = ks * 64 + ((lane >> 4) << 4);
            bf16x8 a = *(const bf16x8*)(hA + row * 256 + (kb ^ ((row & 7) << 4)));
            #pragma unroll
            for (int nt2 = 0; nt2 < 3; ++nt2)
                acc[mt][nt2] = __builtin_amdgcn_mfma_f32_16x16x32_bf16(a, bfr[nt2][ks], acc[mt][nt2], 0, 0, 0);
        }
    }

    // phase 4: epilogue. D: col = lane&15, row = (lane>>4)*4 + reg  [m89-verified]
    #pragma unroll
    for (int mt = 0; mt < 4; ++mt) {
        #pragma unroll
        for (int nt2 = 0; nt2 < 3; ++nt2) {
            int n = w * 48 + nt2 * 16 + (lane & 15);
            #pragma unroll
            for (int r = 0; r < 4; ++r) {
                int e = e0 + mt * 16 + ((lane >> 4) << 2) + r;
                wbuf[(size_t)e * 192 + n] = f2bf(acc[mt][nt2][r]);
            }
        }
    }
}

// ---------------- K2b: per-node gather + TP accumulate (no atomics) -----------
__global__ __launch_bounds__(384) void k_gather(
    const int* __restrict__ start, const int* __restrict__ sorted,
    const int* __restrict__ esrc, const float* __restrict__ eattr,
    const unsigned short* __restrict__ wbuf, const float* __restrict__ x1,
    float* __restrict__ agg)
{
    int n = blockIdx.x;
    int t = threadIdx.x;
    int s0 = start[n], s1 = start[n + 1];

    int widx, gidx, kind, csel = 0;
    float scale;
    if (t < 64)       { widx = t;                gidx = t;              kind = 0; scale = Q_;   }
    else if (t < 96)  { int o = t - 64;          widx = 160 + o; gidx = 64 + 3 * o; kind = 1; scale = Q_S3; }
    else if (t < 288) { int idx = t - 96; int u = idx / 3; csel = idx - 3 * u;
                        widx = 64 + u;           gidx = u;              kind = 2; scale = Q_;   }
    else              { int idx = t - 288; int o = idx / 3; int c = idx - 3 * o;
                        widx = 128 + o;          gidx = 64 + 3 * o + c; kind = 0; scale = Q_;   }

    float acc = 0.f;
    for (int i = s0; i < s1; ++i) {
        int e = sorted[i];
        int src = esrc[e];
        float4 ea = *(const float4*)(eattr + (size_t)e * 4);   // es, ev0, ev1, ev2
        const float* g = x1 + (size_t)src * 160;
        float wv = bf2f(wbuf[(size_t)e * 192 + widx]);
        float contrib;
        if (kind == 0)      contrib = wv * g[gidx] * ea.x;
        else if (kind == 1) contrib = wv * (g[gidx] * ea.y + g[gidx + 1] * ea.z + g[gidx + 2] * ea.w);
        else {
            float evc = (csel == 0) ? ea.y : ((csel == 1) ? ea.z : ea.w);
            contrib = wv * g[gidx] * evc;
        }
        acc += contrib;
    }
    agg[(size_t)n * 384 + t] = acc * scale;
}

// ---------------- fallback K2: fused edge + atomic scatter (known-good) -------
__global__ __launch_bounds__(256) void k_edge(
    const float* __restrict__ ele, const float* __restrict__ eattr,
    const int* __restrict__ esrc, const int* __restrict__ edst,
    const float* __restrict__ Wfc1, const float* __restrict__ Wfc2T,
    const float* __restrict__ x1, float* __restrict__ agg)
{
    int e = blockIdx.x * blockDim.x + threadIdx.x;
    if (e >= NE) return;
    float el[10];
    #pragma unroll
    for (int k = 0; k < 10; ++k) el[k] = ele[(size_t)e * 10 + k];
    float h[100];
    #pragma unroll
    for (int j = 0; j < 100; ++j) {
        float acc = 0.f;
        #pragma unroll
        for (int k = 0; k < 10; ++k) acc += el[k] * Wfc1[k * 100 + j];
        h[j] = acc / (1.f + __expf(-acc));
    }
    int src = esrc[e], dst = edst[e];
    float es  = eattr[(size_t)e * 4 + 0];
    float ev0 = eattr[(size_t)e * 4 + 1];
    float ev1 = eattr[(size_t)e * 4 + 2];
    float ev2 = eattr[(size_t)e * 4 + 3];
    const float* g  = x1 + (size_t)src * 160;
    float*       ag = agg + (size_t)dst * 384;
    for (int o = 0; o < 64; ++o) {
        float w0v = 0.f, w1v = 0.f;
        const float* c0 = Wfc2T + o * 100;
        const float* c1 = Wfc2T + (64 + o) * 100;
        #pragma unroll
        for (int j = 0; j < 100; ++j) { float hj = h[j]; w0v += hj * c0[j]; w1v += hj * c1[j]; }
        float gu = g[o];
        atomicAdd(&ag[o], w0v * gu * es * Q_);
        float b = w1v * gu * Q_;
        atomicAdd(&ag[96 + 3 * o + 0], b * ev0);
        atomicAdd(&ag[96 + 3 * o + 1], b * ev1);
        atomicAdd(&ag[96 + 3 * o + 2], b * ev2);
    }
    for (int o = 0; o < 32; ++o) {
        float w2v = 0.f, w3v = 0.f;
        const float* c2 = Wfc2T + (128 + o) * 100;
        const float* c3 = Wfc2T + (160 + o) * 100;
        #pragma unroll
        for (int j = 0; j < 100; ++j) { float hj = h[j]; w2v += hj * c2[j]; w3v += hj * c3[j]; }
        float g0 = g[64 + 3 * o + 0];
        float g1 = g[64 + 3 * o + 1];
        float g2 = g[64 + 3 * o + 2];
        float b = w2v * es * Q_;
        atomicAdd(&ag[288 + 3 * o + 0], b * g0);
        atomicAdd(&ag[288 + 3 * o + 1], b * g1);
        atomicAdd(&ag[288 + 3 * o + 2], b * g2);
        float dg = g0 * ev0 + g1 * ev1 + g2 * ev2;
        atomicAdd(&ag[64 + o], w3v * dg * Q_S3);
    }
}

// ---------------- K3a: l2 FCTP pair (packed weights) --------------------------
__global__ __launch_bounds__(256) void k_l2(
    const float* __restrict__ agg, const float* __restrict__ attr, const float* __restrict__ cattr,
    const float* __restrict__ W2s, const float* __restrict__ W2v,
    float* __restrict__ l2o)
{
    int t = blockIdx.x * blockDim.x + threadIdx.x;
    if (t >= NN * 384) return;
    int n = t / 384, d = t - n * 384;
    float a = attr[n], c = cattr[n];
    const float* m = agg + (size_t)n * 384;
    float va = 0.f, vc = 0.f;
    if (d < 96) {
        const float2* W = (const float2*)W2s;
        #pragma unroll 8
        for (int k = 0; k < 96; ++k) {
            float x = m[k];
            float2 w = W[k * 96 + d];
            va += x * w.x; vc += x * w.y;
        }
    } else {
        int idx = d - 96;
        int o = idx / 3, cc = idx - o * 3;
        const float2* W = (const float2*)W2v;
        #pragma unroll 8
        for (int u = 0; u < 96; ++u) {
            float x = m[96 + u * 3 + cc];
            float2 w = W[u * 96 + o];
            va += x * w.x; vc += x * w.y;
        }
    }
    l2o[t] = a * va + c * vc;
}

// ---------------- K3b: l3 FCTP + final combine --------------------------------
__global__ __launch_bounds__(256) void k_l3(
    const float* __restrict__ l2o, const float* __restrict__ sym,
    const float* __restrict__ Wl3s, const float* __restrict__ Wl3v,
    float* __restrict__ out)
{
    int t = blockIdx.x * blockDim.x + threadIdx.x;
    if (t >= NN * 160) return;
    int n = t / 160, d = t - n * 160;
    float s = sym[n];
    const float* m = l2o + (size_t)n * 384;
    float acc = 0.f;
    if (d < 64) {
        #pragma unroll 8
        for (int k = 0; k < 96; ++k) acc += m[k] * Wl3s[k * 64 + d];
    } else {
        int idx = d - 64;
        int o = idx / 3, cc = idx - o * 3;
        #pragma unroll 8
        for (int u = 0; u < 96; ++u) acc += m[96 + u * 3 + cc] * Wl3v[u * 32 + o];
    }
    out[t] = out[t] + C_X_ * s * acc;
}

extern "C" void kernel_launch(void* const* d_in, const int* in_sizes, int n_in,
                              void* d_out, int out_size, void* d_ws, size_t ws_size,
                              hipStream_t stream) {
    const float* ni    = (const float*)d_in[0];
    const float* attr  = (const float*)d_in[1];
    const float* cattr = (const float*)d_in[2];
    const float* sym   = (const float*)d_in[3];
    const float* eattr = (const float*)d_in[4];
    const float* ele   = (const float*)d_in[5];
    const int*   esrc  = (const int*)d_in[6];
    const int*   edst  = (const int*)d_in[7];
    const float* Ws_sc_a = (const float*)d_in[8];
    const float* Wv_sc_a = (const float*)d_in[9];
    const float* Ws_sc_c = (const float*)d_in[10];
    const float* Wv_sc_c = (const float*)d_in[11];
    const float* Ws_l1_a = (const float*)d_in[12];
    const float* Wv_l1_a = (const float*)d_in[13];
    const float* Ws_l1_c = (const float*)d_in[14];
    const float* Wv_l1_c = (const float*)d_in[15];
    const float* Wfc1    = (const float*)d_in[16];
    const float* Wfc2    = (const float*)d_in[17];
    const float* Ws_l2_a = (const float*)d_in[18];
    const float* Wv_l2_a = (const float*)d_in[19];
    const float* Ws_l2_c = (const float*)d_in[20];
    const float* Wv_l2_c = (const float*)d_in[21];
    const float* Ws_l3   = (const float*)d_in[22];
    const float* Wv_l3   = (const float*)d_in[23];

    float* out = (float*)d_out;
    float* ws  = (float*)d_ws;
    float* x1    = ws;                        // NN*160
    float* agg   = x1  + (size_t)NN * 160;    // NN*384
    float* l2o   = agg + (size_t)NN * 384;    // NN*384
    float* Wfc2T = l2o + (size_t)NN * 384;    // 19200
    float* W4s   = Wfc2T + 19200;             // 16384
    float* W4v   = W4s + 16384;               // 4096
    float* W2s   = W4v + 4096;                // 18432
    float* W2v   = W2s + 18432;               // 18432
    unsigned short* Wfragb = (unsigned short*)(W2v + 18432);  // 24576 bf16 = 12288 floats

    size_t base_floats = (size_t)NN * 160 + (size_t)NN * 384 * 2
                       + 19200 + 16384 + 4096 + 18432 + 18432 + 12288;
    size_t need_base = base_floats * sizeof(float);
    if (ws_size < need_base) return;

    unsigned short* wbuf = (unsigned short*)(ws + base_floats);     // NE*192 bf16
    int* cnt    = (int*)(wbuf + (size_t)NE * 192);                  // NN
    int* start_ = cnt + NN;                                         // NN+1
    int* cursor = start_ + NN + 1;                                  // NN
    int* sorted = cursor + NN;                                      // NE
    size_t need_fast = need_base + (size_t)NE * 192 * 2
                     + ((size_t)NN * 3 + 1 + (size_t)NE) * sizeof(int);
    bool fast = (ws_size >= need_fast);

    k_pack<<<(67328 + 255) / 256, 256, 0, stream>>>(
        Wfc2, Wfc2T,
        Ws_sc_a, Ws_sc_c, Ws_l1_a, Ws_l1_c, W4s,
        Wv_sc_a, Wv_sc_c, Wv_l1_a, Wv_l1_c, W4v,
        Ws_l2_a, Ws_l2_c, W2s,
        Wv_l2_a, Wv_l2_c, W2v,
        Wfragb);

    k_node_prep<<<(NN * 160 + 255) / 256, 256, 0, stream>>>(
        ni, attr, cattr, W4s, W4v, x1, out);

    if (fast) {
        hipMemsetAsync(cnt, 0, (size_t)NN * sizeof(int), stream);
        k_hist<<<(NE + 255) / 256, 256, 0, stream>>>(edst, cnt);
        k_scan<<<1, 1024, 0, stream>>>(cnt, start_, cursor);
        k_scatter<<<(NE + 255) / 256, 256, 0, stream>>>(edst, cursor, sorted);
        k_edgew_mfma<<<NE / 64, 256, 0, stream>>>(ele, Wfc1, Wfragb, wbuf);
        k_gather<<<NN, 384, 0, stream>>>(start_, sorted, esrc, eattr, wbuf, x1, agg);
    } else {
        hipMemsetAsync(agg, 0, (size_t)NN * 384 * sizeof(float), stream);
        k_edge<<<(NE + 255) / 256, 256, 0, stream>>>(
            ele, eattr, esrc, edst, Wfc1, Wfc2T, x1, agg);
    }

    k_l2<<<(NN * 384 + 255) / 256, 256, 0, stream>>>(
        agg, attr, cattr, W2s, W2v, l2o);

    k_l3<<<(NN * 160 + 255) / 256, 256, 0, stream>>>(
        l2o, sym, Ws_l3, Wv_l3, out);
}

// Round 8
// 673.932 us; speedup vs baseline: 3.3649x; 1.9973x over previous
//
#include <hip/hip_runtime.h>
#include <math.h>

#define NN 25000
#define NE 400000

static constexpr float C_S_ = 0.3826834323650898f;   // sin(pi/8)
static constexpr float C_X_ = 0.9238795325112867f;   // cos(pi/8)
static constexpr float Q_   = 0.25f;                 // 1/sqrt(16)
static constexpr float Q_S3 = 0.25f * 0.5773502691896258f; // Q / sqrt(3)

typedef __attribute__((ext_vector_type(8))) short bf16x8;
typedef __attribute__((ext_vector_type(4))) float f32x4;

__device__ inline unsigned short f2bf(float f) {
    union { float f; unsigned u; } v; v.f = f;
    unsigned r = v.u + 0x7fffu + ((v.u >> 16) & 1u);   // RNE
    return (unsigned short)(r >> 16);
}
__device__ inline float bf2f(unsigned short s) {
    union { unsigned u; float f; } v; v.u = ((unsigned)s) << 16;
    return v.f;
}

// ---------------- K0: pack weights --------------------------------------------
// W4s/W4v: float4 packs for node_prep.
// Wfragb:  bf16 B-frags of Wfc2 [nt<12][ks<4][l<64][i<8]; k=ks*32+(l>>4)*8+i (0 pad k>=100), n=nt*16+(l&15).
// WsabF:   bf16 B-frags of [Wl2sa;Wl2sc] (K=192,N=96): [nt<6][ks<6][l][8].
// WvabF:   same from [Wl2va;Wl2vc].
// Wl3sF:   bf16 B-frags of Ws_l3 (K=96,N=64): [nt<4][ks<3][l][8].
// Wl3vF:   bf16 B-frags of Wv_l3 (K=96,N=32): [nt<2][ks<3][l][8].
__global__ void k_pack(const float* __restrict__ Wfc2,
                       const float* __restrict__ Wsa, const float* __restrict__ Wsc,
                       const float* __restrict__ W1sa, const float* __restrict__ W1sc, float* __restrict__ W4s,
                       const float* __restrict__ Wva, const float* __restrict__ Wvc,
                       const float* __restrict__ W1va, const float* __restrict__ W1vc, float* __restrict__ W4v,
                       const float* __restrict__ Wl2sa, const float* __restrict__ Wl2sc,
                       const float* __restrict__ Wl2va, const float* __restrict__ Wl2vc,
                       const float* __restrict__ Wl3s, const float* __restrict__ Wl3v,
                       unsigned short* __restrict__ Wfragb,
                       unsigned short* __restrict__ WsabF, unsigned short* __restrict__ WvabF,
                       unsigned short* __restrict__ Wl3sF, unsigned short* __restrict__ Wl3vF)
{
    int t = blockIdx.x * blockDim.x + threadIdx.x;
    if (t < 4096) {
        int k = t >> 6, d = t & 63;
        ((float4*)W4s)[k*64+d] = make_float4(Wsa[k*64+d], Wsc[k*64+d], W1sa[k*64+d], W1sc[k*64+d]);
        return;
    }
    t -= 4096;
    if (t < 1024) {
        int u = t >> 5, o = t & 31;
        ((float4*)W4v)[u*32+o] = make_float4(Wva[u*32+o], Wvc[u*32+o], W1va[u*32+o], W1vc[u*32+o]);
        return;
    }
    t -= 1024;
    if (t < 24576) {
        int i = t & 7, l = (t >> 3) & 63, ks = (t >> 9) & 3, nt = t >> 11;
        int k = ks * 32 + ((l >> 4) << 3) + i;
        int n = nt * 16 + (l & 15);
        Wfragb[t] = (k < 100) ? f2bf(Wfc2[k * 192 + n]) : (unsigned short)0;
        return;
    }
    t -= 24576;
    if (t < 18432) {
        int i = t & 7, l = (t >> 3) & 63, rem = t >> 9;
        int ks = rem % 6, nt = rem / 6;
        int k = ks * 32 + ((l >> 4) << 3) + i;
        int n = nt * 16 + (l & 15);
        WsabF[t] = f2bf(k < 96 ? Wl2sa[k * 96 + n] : Wl2sc[(k - 96) * 96 + n]);
        return;
    }
    t -= 18432;
    if (t < 18432) {
        int i = t & 7, l = (t >> 3) & 63, rem = t >> 9;
        int ks = rem % 6, nt = rem / 6;
        int k = ks * 32 + ((l >> 4) << 3) + i;
        int n = nt * 16 + (l & 15);
        WvabF[t] = f2bf(k < 96 ? Wl2va[k * 96 + n] : Wl2vc[(k - 96) * 96 + n]);
        return;
    }
    t -= 18432;
    if (t < 6144) {
        int i = t & 7, l = (t >> 3) & 63, rem = t >> 9;
        int ks = rem % 3, nt = rem / 3;
        int k = ks * 32 + ((l >> 4) << 3) + i;
        int n = nt * 16 + (l & 15);
        Wl3sF[t] = f2bf(Wl3s[k * 64 + n]);
        return;
    }
    t -= 6144;
    if (t < 3072) {
        int i = t & 7, l = (t >> 3) & 63, rem = t >> 9;
        int ks = rem % 3, nt = rem / 3;
        int k = ks * 32 + ((l >> 4) << 3) + i;
        int n = nt * 16 + (l & 15);
        Wl3vF[t] = f2bf(Wl3v[k * 32 + n]);
        return;
    }
}

// ---------------- K1: node prep (packed weights) ------------------------------
__global__ __launch_bounds__(256) void k_node_prep(
    const float* __restrict__ ni, const float* __restrict__ attr, const float* __restrict__ cattr,
    const float* __restrict__ W4s, const float* __restrict__ W4v,
    float* __restrict__ x1, float* __restrict__ out)
{
    int t = blockIdx.x * blockDim.x + threadIdx.x;
    if (t >= NN * 160) return;
    int n = t / 160, d = t - n * 160;
    float a = attr[n], c = cattr[n];
    const float* row = ni + (size_t)n * 160;
    float ssa = 0.f, ssc = 0.f, s1a = 0.f, s1c = 0.f;
    if (d < 64) {
        const float4* W = (const float4*)W4s;
        #pragma unroll
        for (int k = 0; k < 64; ++k) {
            float x = row[k];
            float4 w = W[k * 64 + d];
            ssa += x * w.x; ssc += x * w.y; s1a += x * w.z; s1c += x * w.w;
        }
    } else {
        int idx = d - 64;
        int o = idx / 3, cc = idx - o * 3;
        const float4* W = (const float4*)W4v;
        #pragma unroll
        for (int u = 0; u < 32; ++u) {
            float x = row[64 + u * 3 + cc];
            float4 w = W[u * 32 + o];
            ssa += x * w.x; ssc += x * w.y; s1a += x * w.z; s1c += x * w.w;
        }
    }
    x1[t]  = a * s1a + c * s1c;
    out[t] = C_S_ * (a * ssa + c * ssc);
}

// ---------------- sort: histogram ---------------------------------------------
__global__ __launch_bounds__(256) void k_hist(const int* __restrict__ edst, int* __restrict__ cnt) {
    int e = blockIdx.x * blockDim.x + threadIdx.x;
    if (e >= NE) return;
    atomicAdd(&cnt[edst[e]], 1);
}

// ---------------- sort: single-block exclusive scan over NN counts ------------
__global__ __launch_bounds__(1024) void k_scan(const int* __restrict__ cnt,
                                               int* __restrict__ start, int* __restrict__ cursor) {
    __shared__ int wsum[16];
    __shared__ int carry_s;
    int lane = threadIdx.x & 63, wid = threadIdx.x >> 6;
    if (threadIdx.x == 0) carry_s = 0;
    __syncthreads();
    for (int base = 0; base < NN; base += 1024) {
        int i = base + threadIdx.x;
        int v = (i < NN) ? cnt[i] : 0;
        int x = v;
        #pragma unroll
        for (int off = 1; off < 64; off <<= 1) {
            int y = __shfl_up(x, off, 64);
            if (lane >= off) x += y;
        }
        if (lane == 63) wsum[wid] = x;
        __syncthreads();
        if (wid == 0 && lane < 16) {
            int s = wsum[lane];
            #pragma unroll
            for (int off = 1; off < 16; off <<= 1) {
                int y = __shfl_up(s, off, 64);
                if (lane >= off) s += y;
            }
            wsum[lane] = s;
        }
        __syncthreads();
        int woff = (wid > 0) ? wsum[wid - 1] : 0;
        int excl = x - v + woff + carry_s;
        if (i < NN) { start[i] = excl; cursor[i] = excl; }
        __syncthreads();
        if (threadIdx.x == 1023) carry_s += wsum[15];
        __syncthreads();
    }
    if (threadIdx.x == 0) start[NN] = NE;
}

// ---------------- sort: scatter edge ids --------------------------------------
__global__ __launch_bounds__(256) void k_scatter(const int* __restrict__ edst,
                                                 int* __restrict__ cursor,
                                                 int* __restrict__ sorted) {
    int e = blockIdx.x * blockDim.x + threadIdx.x;
    if (e >= NE) return;
    int p = atomicAdd(&cursor[edst[e]], 1);
    sorted[p] = e;
}

// ---------------- K2a: MFMA edge-weight GEMM ----------------------------------
__global__ __launch_bounds__(256, 2) void k_edgew_mfma(
    const float* __restrict__ ele,
    const float* __restrict__ Wfc1, const unsigned short* __restrict__ Wfragb,
    unsigned short* __restrict__ wbuf)
{
    __shared__ float ele_s[640];
    __shared__ char  hA[64 * 256];      // [row=edge][128 bf16], byte ^= (row&7)<<4

    int tid  = threadIdx.x;
    int lane = tid & 63;
    int w    = tid >> 6;
    int e0   = blockIdx.x * 64;

    for (int idx = tid; idx < 640; idx += 256)
        ele_s[idx] = ele[(size_t)e0 * 10 + idx];
    __syncthreads();

    #pragma unroll 1
    for (int it = 0; it < 25; ++it) {
        int t2 = tid + it * 256;
        int e_loc = t2 & 63;
        int j = t2 >> 6;
        const float* elp = ele_s + e_loc * 10;
        float acc = 0.f;
        #pragma unroll
        for (int k = 0; k < 10; ++k) acc += elp[k] * Wfc1[k * 100 + j];
        float hv = acc / (1.f + __expf(-acc));
        int col2 = j * 2;
        *(unsigned short*)(hA + e_loc * 256 + (col2 ^ ((e_loc & 7) << 4))) = f2bf(hv);
    }
    for (int idx = tid; idx < 64 * 28; idx += 256) {
        int e_loc = idx / 28;
        int col2 = (100 + (idx - e_loc * 28)) * 2;
        *(unsigned short*)(hA + e_loc * 256 + (col2 ^ ((e_loc & 7) << 4))) = 0;
    }
    __syncthreads();

    const bf16x8* Wv = (const bf16x8*)Wfragb;
    bf16x8 bfr[3][4];
    #pragma unroll
    for (int nt2 = 0; nt2 < 3; ++nt2)
        #pragma unroll
        for (int ks = 0; ks < 4; ++ks)
            bfr[nt2][ks] = Wv[(((w * 3 + nt2) * 4) + ks) * 64 + lane];

    f32x4 acc[4][3];
    #pragma unroll
    for (int mt = 0; mt < 4; ++mt)
        #pragma unroll
        for (int nt2 = 0; nt2 < 3; ++nt2)
            acc[mt][nt2] = (f32x4)0.f;

    #pragma unroll
    for (int mt = 0; mt < 4; ++mt) {
        int row = mt * 16 + (lane & 15);
        #pragma unroll
        for (int ks = 0; ks < 4; ++ks) {
            int kb = ks * 64 + ((lane >> 4) << 4);
            bf16x8 a = *(const bf16x8*)(hA + row * 256 + (kb ^ ((row & 7) << 4)));
            #pragma unroll
            for (int nt2 = 0; nt2 < 3; ++nt2)
                acc[mt][nt2] = __builtin_amdgcn_mfma_f32_16x16x32_bf16(a, bfr[nt2][ks], acc[mt][nt2], 0, 0, 0);
        }
    }

    #pragma unroll
    for (int mt = 0; mt < 4; ++mt) {
        #pragma unroll
        for (int nt2 = 0; nt2 < 3; ++nt2) {
            int n = w * 48 + nt2 * 16 + (lane & 15);
            #pragma unroll
            for (int r = 0; r < 4; ++r) {
                int e = e0 + mt * 16 + ((lane >> 4) << 2) + r;
                wbuf[(size_t)e * 192 + n] = f2bf(acc[mt][nt2][r]);
            }
        }
    }
}

// ---------------- K2b: per-node gather + TP accumulate (no atomics) -----------
__global__ __launch_bounds__(384) void k_gather(
    const int* __restrict__ start, const int* __restrict__ sorted,
    const int* __restrict__ esrc, const float* __restrict__ eattr,
    const unsigned short* __restrict__ wbuf, const float* __restrict__ x1,
    float* __restrict__ agg)
{
    int n = blockIdx.x;
    int t = threadIdx.x;
    int s0 = start[n], s1 = start[n + 1];

    int widx, gidx, kind, csel = 0;
    float scale;
    if (t < 64)       { widx = t;                gidx = t;              kind = 0; scale = Q_;   }
    else if (t < 96)  { int o = t - 64;          widx = 160 + o; gidx = 64 + 3 * o; kind = 1; scale = Q_S3; }
    else if (t < 288) { int idx = t - 96; int u = idx / 3; csel = idx - 3 * u;
                        widx = 64 + u;           gidx = u;              kind = 2; scale = Q_;   }
    else              { int idx = t - 288; int o = idx / 3; int c = idx - 3 * o;
                        widx = 128 + o;          gidx = 64 + 3 * o + c; kind = 0; scale = Q_;   }

    float acc = 0.f;
    for (int i = s0; i < s1; ++i) {
        int e = sorted[i];
        int src = esrc[e];
        float4 ea = *(const float4*)(eattr + (size_t)e * 4);
        const float* g = x1 + (size_t)src * 160;
        float wv = bf2f(wbuf[(size_t)e * 192 + widx]);
        float contrib;
        if (kind == 0)      contrib = wv * g[gidx] * ea.x;
        else if (kind == 1) contrib = wv * (g[gidx] * ea.y + g[gidx + 1] * ea.z + g[gidx + 2] * ea.w);
        else {
            float evc = (csel == 0) ? ea.y : ((csel == 1) ? ea.z : ea.w);
            contrib = wv * g[gidx] * evc;
        }
        acc += contrib;
    }
    agg[(size_t)n * 384 + t] = acc * scale;
}

// ---------------- K3: fused l2+l3 double-MFMA ---------------------------------
// grid (391, 4): slot 0 = scalar path, slot 1..3 = vector component cc=slot-1.
// Stage 1: A1[64][192] bf16 = [a*m | c*m] (attr blend folded into input), K=192
//          GEMM vs WsabF/WvabF -> m2 [64][96] in acc (fp32).
// Stage 2: m2 -> bf16 A2 (wave-private LDS rows), K=96 GEMM vs Wl3 frags.
// Epilogue: out[n][d] += C_X * sym[n] * val.
__global__ __launch_bounds__(256, 2) void k_l23(
    const float* __restrict__ agg, const float* __restrict__ attr,
    const float* __restrict__ cattr, const float* __restrict__ sym,
    const unsigned short* __restrict__ WsabF, const unsigned short* __restrict__ WvabF,
    const unsigned short* __restrict__ Wl3sF, const unsigned short* __restrict__ Wl3vF,
    float* __restrict__ out)
{
    __shared__ char A1[64 * 512];   // rows padded to 512B so XOR swizzle stays in-row
    __shared__ char A2[64 * 256];

    int slot = blockIdx.y;
    int cc   = slot - 1;
    int n0   = blockIdx.x * 64;
    int tid  = threadIdx.x, lane = tid & 63, w = tid >> 6;

    // build A1: logical col km<96 -> a*val, col 96+km -> c*val
    for (int idx = tid; idx < 64 * 96; idx += 256) {
        int r = idx / 96, km = idx - r * 96;
        int n = n0 + r;
        float a = 0.f, cv = 0.f, val = 0.f;
        if (n < NN) {
            a = attr[n]; cv = cattr[n];
            int src = (slot == 0) ? km : (96 + 3 * km + cc);
            val = agg[(size_t)n * 384 + src];
        }
        int sw = (r & 7) << 4;
        *(unsigned short*)(A1 + r * 512 + ((2 * km) ^ sw))         = f2bf(a  * val);
        *(unsigned short*)(A1 + r * 512 + ((192 + 2 * km) ^ sw))   = f2bf(cv * val);
    }
    __syncthreads();

    const unsigned short* Bf = (slot == 0) ? WsabF : WvabF;
    f32x4 acc1[6];
    #pragma unroll
    for (int nt = 0; nt < 6; ++nt) acc1[nt] = (f32x4)0.f;

    int arow = w * 16 + (lane & 15);
    int asw  = (arow & 7) << 4;
    #pragma unroll
    for (int ks = 0; ks < 6; ++ks) {
        int kb = ks * 64 + ((lane >> 4) << 4);
        bf16x8 af = *(const bf16x8*)(A1 + arow * 512 + (kb ^ asw));
        #pragma unroll
        for (int nt = 0; nt < 6; ++nt) {
            bf16x8 bfrag = *(const bf16x8*)(Bf + (size_t)(((nt * 6 + ks) * 64) + lane) * 8);
            acc1[nt] = __builtin_amdgcn_mfma_f32_16x16x32_bf16(af, bfrag, acc1[nt], 0, 0, 0);
        }
    }

    // m2 -> A2 bf16, wave-private rows (no block sync needed)
    #pragma unroll
    for (int nt = 0; nt < 6; ++nt) {
        int ncol2 = (nt * 16 + (lane & 15)) * 2;
        #pragma unroll
        for (int r = 0; r < 4; ++r) {
            int row = w * 16 + ((lane >> 4) << 2) + r;
            *(unsigned short*)(A2 + row * 256 + (ncol2 ^ ((row & 7) << 4))) = f2bf(acc1[nt][r]);
        }
    }

    int NT2 = (slot == 0) ? 4 : 2;
    const unsigned short* B2 = (slot == 0) ? Wl3sF : Wl3vF;
    f32x4 acc2[4];
    #pragma unroll
    for (int nt2 = 0; nt2 < 4; ++nt2) acc2[nt2] = (f32x4)0.f;

    #pragma unroll
    for (int ks = 0; ks < 3; ++ks) {
        int kb = ks * 64 + ((lane >> 4) << 4);
        bf16x8 a2 = *(const bf16x8*)(A2 + arow * 256 + (kb ^ ((arow & 7) << 4)));
        #pragma unroll
        for (int nt2 = 0; nt2 < 4; ++nt2) {
            if (nt2 < NT2) {
                bf16x8 b2 = *(const bf16x8*)(B2 + (size_t)(((nt2 * 3 + ks) * 64) + lane) * 8);
                acc2[nt2] = __builtin_amdgcn_mfma_f32_16x16x32_bf16(a2, b2, acc2[nt2], 0, 0, 0);
            }
        }
    }

    #pragma unroll
    for (int r = 0; r < 4; ++r) {
        int n = n0 + w * 16 + ((lane >> 4) << 2) + r;
        if (n >= NN) continue;
        float sv = C_X_ * sym[n];
        #pragma unroll
        for (int nt2 = 0; nt2 < 4; ++nt2) {
            if (nt2 < NT2) {
                int col = nt2 * 16 + (lane & 15);
                int d = (slot == 0) ? col : (64 + 3 * col + cc);
                out[(size_t)n * 160 + d] += sv * acc2[nt2][r];
            }
        }
    }
}

extern "C" void kernel_launch(void* const* d_in, const int* in_sizes, int n_in,
                              void* d_out, int out_size, void* d_ws, size_t ws_size,
                              hipStream_t stream) {
    const float* ni    = (const float*)d_in[0];
    const float* attr  = (const float*)d_in[1];
    const float* cattr = (const float*)d_in[2];
    const float* sym   = (const float*)d_in[3];
    const float* eattr = (const float*)d_in[4];
    const float* ele   = (const float*)d_in[5];
    const int*   esrc  = (const int*)d_in[6];
    const int*   edst  = (const int*)d_in[7];
    const float* Ws_sc_a = (const float*)d_in[8];
    const float* Wv_sc_a = (const float*)d_in[9];
    const float* Ws_sc_c = (const float*)d_in[10];
    const float* Wv_sc_c = (const float*)d_in[11];
    const float* Ws_l1_a = (const float*)d_in[12];
    const float* Wv_l1_a = (const float*)d_in[13];
    const float* Ws_l1_c = (const float*)d_in[14];
    const float* Wv_l1_c = (const float*)d_in[15];
    const float* Wfc1    = (const float*)d_in[16];
    const float* Wfc2    = (const float*)d_in[17];
    const float* Ws_l2_a = (const float*)d_in[18];
    const float* Wv_l2_a = (const float*)d_in[19];
    const float* Ws_l2_c = (const float*)d_in[20];
    const float* Wv_l2_c = (const float*)d_in[21];
    const float* Ws_l3   = (const float*)d_in[22];
    const float* Wv_l3   = (const float*)d_in[23];

    float* out = (float*)d_out;
    float* ws  = (float*)d_ws;
    float* x1  = ws;                          // NN*160
    float* agg = x1 + (size_t)NN * 160;       // NN*384
    float* W4s = agg + (size_t)NN * 384;      // 16384
    float* W4v = W4s + 16384;                 // 4096
    unsigned short* Wfragb = (unsigned short*)(W4v + 4096);  // 24576
    unsigned short* WsabF  = Wfragb + 24576;                 // 18432
    unsigned short* WvabF  = WsabF + 18432;                  // 18432
    unsigned short* Wl3sF  = WvabF + 18432;                  // 6144
    unsigned short* Wl3vF  = Wl3sF + 6144;                   // 3072
    unsigned short* wbuf   = Wl3vF + 3072;                   // NE*192
    int* cnt    = (int*)(wbuf + (size_t)NE * 192);           // NN
    int* start_ = cnt + NN;                                  // NN+1
    int* cursor = start_ + NN + 1;                           // NN
    int* sorted = cursor + NN;                               // NE

    size_t need = ((size_t)NN * 160 + (size_t)NN * 384 + 16384 + 4096) * 4
                + ((size_t)24576 + 18432 + 18432 + 6144 + 3072 + (size_t)NE * 192) * 2
                + ((size_t)NN * 3 + 1 + NE) * 4;
    if (ws_size < need) return;   // proven to fit in R4-R7 (need shrank since)

    k_pack<<<(75776 + 255) / 256, 256, 0, stream>>>(
        Wfc2,
        Ws_sc_a, Ws_sc_c, Ws_l1_a, Ws_l1_c, W4s,
        Wv_sc_a, Wv_sc_c, Wv_l1_a, Wv_l1_c, W4v,
        Ws_l2_a, Ws_l2_c, Wv_l2_a, Wv_l2_c,
        Ws_l3, Wv_l3,
        Wfragb, WsabF, WvabF, Wl3sF, Wl3vF);

    k_node_prep<<<(NN * 160 + 255) / 256, 256, 0, stream>>>(
        ni, attr, cattr, W4s, W4v, x1, out);

    hipMemsetAsync(cnt, 0, (size_t)NN * sizeof(int), stream);
    k_hist<<<(NE + 255) / 256, 256, 0, stream>>>(edst, cnt);
    k_scan<<<1, 1024, 0, stream>>>(cnt, start_, cursor);
    k_scatter<<<(NE + 255) / 256, 256, 0, stream>>>(edst, cursor, sorted);
    k_edgew_mfma<<<NE / 64, 256, 0, stream>>>(ele, Wfc1, Wfragb, wbuf);
    k_gather<<<NN, 384, 0, stream>>>(start_, sorted, esrc, eattr, wbuf, x1, agg);

    k_l23<<<dim3((NN + 63) / 64, 4), 256, 0, stream>>>(
        agg, attr, cattr, sym, WsabF, WvabF, Wl3sF, Wl3vF, out);
}

// Round 10
// 667.150 us; speedup vs baseline: 3.3992x; 1.0102x over previous
//
#include <hip/hip_runtime.h>
#include <math.h>

#define NN 25000
#define NE 400000

static constexpr float C_S_ = 0.3826834323650898f;   // sin(pi/8)
static constexpr float C_X_ = 0.9238795325112867f;   // cos(pi/8)
static constexpr float Q_   = 0.25f;                 // 1/sqrt(16)
static constexpr float Q_S3 = 0.25f * 0.5773502691896258f; // Q / sqrt(3)

typedef __attribute__((ext_vector_type(8))) short bf16x8;
typedef __attribute__((ext_vector_type(4))) float f32x4;

__device__ inline unsigned short f2bf(float f) {
    union { float f; unsigned u; } v; v.f = f;
    unsigned r = v.u + 0x7fffu + ((v.u >> 16) & 1u);   // RNE
    return (unsigned short)(r >> 16);
}
__device__ inline float bf2f(unsigned short s) {
    union { unsigned u; float f; } v; v.u = ((unsigned)s) << 16;
    return v.f;
}

// ---------------- K0: pack weights --------------------------------------------
__global__ void k_pack(const float* __restrict__ Wfc2,
                       const float* __restrict__ Wsa, const float* __restrict__ Wsc,
                       const float* __restrict__ W1sa, const float* __restrict__ W1sc, float* __restrict__ W4s,
                       const float* __restrict__ Wva, const float* __restrict__ Wvc,
                       const float* __restrict__ W1va, const float* __restrict__ W1vc, float* __restrict__ W4v,
                       const float* __restrict__ Wl2sa, const float* __restrict__ Wl2sc,
                       const float* __restrict__ Wl2va, const float* __restrict__ Wl2vc,
                       const float* __restrict__ Wl3s, const float* __restrict__ Wl3v,
                       unsigned short* __restrict__ Wfragb,
                       unsigned short* __restrict__ WsabF, unsigned short* __restrict__ WvabF,
                       unsigned short* __restrict__ Wl3sF, unsigned short* __restrict__ Wl3vF)
{
    int t = blockIdx.x * blockDim.x + threadIdx.x;
    if (t < 4096) {
        int k = t >> 6, d = t & 63;
        ((float4*)W4s)[k*64+d] = make_float4(Wsa[k*64+d], Wsc[k*64+d], W1sa[k*64+d], W1sc[k*64+d]);
        return;
    }
    t -= 4096;
    if (t < 1024) {
        int u = t >> 5, o = t & 31;
        ((float4*)W4v)[u*32+o] = make_float4(Wva[u*32+o], Wvc[u*32+o], W1va[u*32+o], W1vc[u*32+o]);
        return;
    }
    t -= 1024;
    if (t < 24576) {
        int i = t & 7, l = (t >> 3) & 63, ks = (t >> 9) & 3, nt = t >> 11;
        int k = ks * 32 + ((l >> 4) << 3) + i;
        int n = nt * 16 + (l & 15);
        Wfragb[t] = (k < 100) ? f2bf(Wfc2[k * 192 + n]) : (unsigned short)0;
        return;
    }
    t -= 24576;
    if (t < 18432) {
        int i = t & 7, l = (t >> 3) & 63, rem = t >> 9;
        int ks = rem % 6, nt = rem / 6;
        int k = ks * 32 + ((l >> 4) << 3) + i;
        int n = nt * 16 + (l & 15);
        WsabF[t] = f2bf(k < 96 ? Wl2sa[k * 96 + n] : Wl2sc[(k - 96) * 96 + n]);
        return;
    }
    t -= 18432;
    if (t < 18432) {
        int i = t & 7, l = (t >> 3) & 63, rem = t >> 9;
        int ks = rem % 6, nt = rem / 6;
        int k = ks * 32 + ((l >> 4) << 3) + i;
        int n = nt * 16 + (l & 15);
        WvabF[t] = f2bf(k < 96 ? Wl2va[k * 96 + n] : Wl2vc[(k - 96) * 96 + n]);
        return;
    }
    t -= 18432;
    if (t < 6144) {
        int i = t & 7, l = (t >> 3) & 63, rem = t >> 9;
        int ks = rem % 3, nt = rem / 3;
        int k = ks * 32 + ((l >> 4) << 3) + i;
        int n = nt * 16 + (l & 15);
        Wl3sF[t] = f2bf(Wl3s[k * 64 + n]);
        return;
    }
    t -= 6144;
    if (t < 3072) {
        int i = t & 7, l = (t >> 3) & 63, rem = t >> 9;
        int ks = rem % 3, nt = rem / 3;
        int k = ks * 32 + ((l >> 4) << 3) + i;
        int n = nt * 16 + (l & 15);
        Wl3vF[t] = f2bf(Wl3v[k * 32 + n]);
        return;
    }
}

// ---------------- K1: node prep (packed weights) ------------------------------
__global__ __launch_bounds__(256) void k_node_prep(
    const float* __restrict__ ni, const float* __restrict__ attr, const float* __restrict__ cattr,
    const float* __restrict__ W4s, const float* __restrict__ W4v,
    float* __restrict__ x1, float* __restrict__ out)
{
    int t = blockIdx.x * blockDim.x + threadIdx.x;
    if (t >= NN * 160) return;
    int n = t / 160, d = t - n * 160;
    float a = attr[n], c = cattr[n];
    const float* row = ni + (size_t)n * 160;
    float ssa = 0.f, ssc = 0.f, s1a = 0.f, s1c = 0.f;
    if (d < 64) {
        const float4* W = (const float4*)W4s;
        #pragma unroll
        for (int k = 0; k < 64; ++k) {
            float x = row[k];
            float4 w = W[k * 64 + d];
            ssa += x * w.x; ssc += x * w.y; s1a += x * w.z; s1c += x * w.w;
        }
    } else {
        int idx = d - 64;
        int o = idx / 3, cc = idx - o * 3;
        const float4* W = (const float4*)W4v;
        #pragma unroll
        for (int u = 0; u < 32; ++u) {
            float x = row[64 + u * 3 + cc];
            float4 w = W[u * 32 + o];
            ssa += x * w.x; ssc += x * w.y; s1a += x * w.z; s1c += x * w.w;
        }
    }
    x1[t]  = a * s1a + c * s1c;
    out[t] = C_S_ * (a * ssa + c * ssc);
}

// ---------------- sort: histogram ---------------------------------------------
__global__ __launch_bounds__(256) void k_hist(const int* __restrict__ edst, int* __restrict__ cnt) {
    int e = blockIdx.x * blockDim.x + threadIdx.x;
    if (e >= NE) return;
    atomicAdd(&cnt[edst[e]], 1);
}

// ---------------- sort: single-block exclusive scan over NN counts ------------
__global__ __launch_bounds__(1024) void k_scan(const int* __restrict__ cnt,
                                               int* __restrict__ start, int* __restrict__ cursor) {
    __shared__ int wsum[16];
    __shared__ int carry_s;
    int lane = threadIdx.x & 63, wid = threadIdx.x >> 6;
    if (threadIdx.x == 0) carry_s = 0;
    __syncthreads();
    for (int base = 0; base < NN; base += 1024) {
        int i = base + threadIdx.x;
        int v = (i < NN) ? cnt[i] : 0;
        int x = v;
        #pragma unroll
        for (int off = 1; off < 64; off <<= 1) {
            int y = __shfl_up(x, off, 64);
            if (lane >= off) x += y;
        }
        if (lane == 63) wsum[wid] = x;
        __syncthreads();
        if (wid == 0 && lane < 16) {
            int s = wsum[lane];
            #pragma unroll
            for (int off = 1; off < 16; off <<= 1) {
                int y = __shfl_up(s, off, 64);
                if (lane >= off) s += y;
            }
            wsum[lane] = s;
        }
        __syncthreads();
        int woff = (wid > 0) ? wsum[wid - 1] : 0;
        int excl = x - v + woff + carry_s;
        if (i < NN) { start[i] = excl; cursor[i] = excl; }
        __syncthreads();
        if (threadIdx.x == 1023) carry_s += wsum[15];
        __syncthreads();
    }
    if (threadIdx.x == 0) start[NN] = NE;
}

// ---------------- sort: scatter edge ids --------------------------------------
__global__ __launch_bounds__(256) void k_scatter(const int* __restrict__ edst,
                                                 int* __restrict__ cursor,
                                                 int* __restrict__ sorted) {
    int e = blockIdx.x * blockDim.x + threadIdx.x;
    if (e >= NE) return;
    int p = atomicAdd(&cursor[edst[e]], 1);
    sorted[p] = e;
}

// ---------------- K2a: MFMA edge-weight GEMM ----------------------------------
__global__ __launch_bounds__(256, 2) void k_edgew_mfma(
    const float* __restrict__ ele,
    const float* __restrict__ Wfc1, const unsigned short* __restrict__ Wfragb,
    unsigned short* __restrict__ wbuf)
{
    __shared__ float ele_s[640];
    __shared__ char  hA[64 * 256];      // [row=edge][128 bf16], byte ^= (row&7)<<4

    int tid  = threadIdx.x;
    int lane = tid & 63;
    int w    = tid >> 6;
    int e0   = blockIdx.x * 64;

    for (int idx = tid; idx < 640; idx += 256)
        ele_s[idx] = ele[(size_t)e0 * 10 + idx];
    __syncthreads();

    #pragma unroll 1
    for (int it = 0; it < 25; ++it) {
        int t2 = tid + it * 256;
        int e_loc = t2 & 63;
        int j = t2 >> 6;
        const float* elp = ele_s + e_loc * 10;
        float acc = 0.f;
        #pragma unroll
        for (int k = 0; k < 10; ++k) acc += elp[k] * Wfc1[k * 100 + j];
        float hv = acc / (1.f + __expf(-acc));
        int col2 = j * 2;
        *(unsigned short*)(hA + e_loc * 256 + (col2 ^ ((e_loc & 7) << 4))) = f2bf(hv);
    }
    for (int idx = tid; idx < 64 * 28; idx += 256) {
        int e_loc = idx / 28;
        int col2 = (100 + (idx - e_loc * 28)) * 2;
        *(unsigned short*)(hA + e_loc * 256 + (col2 ^ ((e_loc & 7) << 4))) = 0;
    }
    __syncthreads();

    const bf16x8* Wv = (const bf16x8*)Wfragb;
    bf16x8 bfr[3][4];
    #pragma unroll
    for (int nt2 = 0; nt2 < 3; ++nt2)
        #pragma unroll
        for (int ks = 0; ks < 4; ++ks)
            bfr[nt2][ks] = Wv[(((w * 3 + nt2) * 4) + ks) * 64 + lane];

    f32x4 acc[4][3];
    #pragma unroll
    for (int mt = 0; mt < 4; ++mt)
        #pragma unroll
        for (int nt2 = 0; nt2 < 3; ++nt2)
            acc[mt][nt2] = (f32x4)0.f;

    #pragma unroll
    for (int mt = 0; mt < 4; ++mt) {
        int row = mt * 16 + (lane & 15);
        #pragma unroll
        for (int ks = 0; ks < 4; ++ks) {
            int kb = ks * 64 + ((lane >> 4) << 4);
            bf16x8 a = *(const bf16x8*)(hA + row * 256 + (kb ^ ((row & 7) << 4)));
            #pragma unroll
            for (int nt2 = 0; nt2 < 3; ++nt2)
                acc[mt][nt2] = __builtin_amdgcn_mfma_f32_16x16x32_bf16(a, bfr[nt2][ks], acc[mt][nt2], 0, 0, 0);
        }
    }

    #pragma unroll
    for (int mt = 0; mt < 4; ++mt) {
        #pragma unroll
        for (int nt2 = 0; nt2 < 3; ++nt2) {
            int n = w * 48 + nt2 * 16 + (lane & 15);
            #pragma unroll
            for (int r = 0; r < 4; ++r) {
                int e = e0 + mt * 16 + ((lane >> 4) << 2) + r;
                wbuf[(size_t)e * 192 + n] = f2bf(acc[mt][nt2][r]);
            }
        }
    }
}

// ---------------- K2b: per-node gather, unroll-4 for MLP latency hiding -------
__global__ __launch_bounds__(384) void k_gather(
    const int* __restrict__ start, const int* __restrict__ sorted,
    const int* __restrict__ esrc, const float* __restrict__ eattr,
    const unsigned short* __restrict__ wbuf, const float* __restrict__ x1,
    float* __restrict__ agg)
{
    int n = blockIdx.x;
    int t = threadIdx.x;
    int s0 = start[n], s1 = start[n + 1];

    int widx, gidx, kind, csel = 0;
    float scale;
    if (t < 64)       { widx = t;                gidx = t;              kind = 0; scale = Q_;   }
    else if (t < 96)  { int o = t - 64;          widx = 160 + o; gidx = 64 + 3 * o; kind = 1; scale = Q_S3; }
    else if (t < 288) { int idx = t - 96; int u = idx / 3; csel = idx - 3 * u;
                        widx = 64 + u;           gidx = u;              kind = 2; scale = Q_;   }
    else              { int idx = t - 288; int o = idx / 3; int c = idx - 3 * o;
                        widx = 128 + o;          gidx = 64 + 3 * o + c; kind = 0; scale = Q_;   }

    #define CONTRIB(e, dst)                                                        \
    {                                                                              \
        int src = esrc[e];                                                         \
        float4 ea = *(const float4*)(eattr + (size_t)(e) * 4);                     \
        const float* g = x1 + (size_t)src * 160;                                   \
        float wv = bf2f(wbuf[(size_t)(e) * 192 + widx]);                           \
        if (kind == 0)      dst += wv * g[gidx] * ea.x;                            \
        else if (kind == 1) dst += wv * (g[gidx] * ea.y + g[gidx+1] * ea.z + g[gidx+2] * ea.w); \
        else {                                                                     \
            float evc = (csel == 0) ? ea.y : ((csel == 1) ? ea.z : ea.w);          \
            dst += wv * g[gidx] * evc;                                             \
        }                                                                          \
    }

    float a0 = 0.f, a1 = 0.f, a2 = 0.f, a3 = 0.f;
    int i = s0;
    for (; i + 4 <= s1; i += 4) {
        int e0 = sorted[i + 0];
        int e1 = sorted[i + 1];
        int e2 = sorted[i + 2];
        int e3 = sorted[i + 3];
        CONTRIB(e0, a0);
        CONTRIB(e1, a1);
        CONTRIB(e2, a2);
        CONTRIB(e3, a3);
    }
    for (; i < s1; ++i) {
        int e = sorted[i];
        CONTRIB(e, a0);
    }
    #undef CONTRIB

    agg[(size_t)n * 384 + t] = ((a0 + a1) + (a2 + a3)) * scale;
}

// ---------------- K3: fused l2+l3 double-MFMA ---------------------------------
__global__ __launch_bounds__(256, 2) void k_l23(
    const float* __restrict__ agg, const float* __restrict__ attr,
    const float* __restrict__ cattr, const float* __restrict__ sym,
    const unsigned short* __restrict__ WsabF, const unsigned short* __restrict__ WvabF,
    const unsigned short* __restrict__ Wl3sF, const unsigned short* __restrict__ Wl3vF,
    float* __restrict__ out)
{
    __shared__ char A1[64 * 512];   // rows padded to 512B so XOR swizzle stays in-row
    __shared__ char A2[64 * 256];

    int slot = blockIdx.y;
    int cc   = slot - 1;
    int n0   = blockIdx.x * 64;
    int tid  = threadIdx.x, lane = tid & 63, w = tid >> 6;

    for (int idx = tid; idx < 64 * 96; idx += 256) {
        int r = idx / 96, km = idx - r * 96;
        int n = n0 + r;
        float a = 0.f, cv = 0.f, val = 0.f;
        if (n < NN) {
            a = attr[n]; cv = cattr[n];
            int src = (slot == 0) ? km : (96 + 3 * km + cc);
            val = agg[(size_t)n * 384 + src];
        }
        int sw = (r & 7) << 4;
        *(unsigned short*)(A1 + r * 512 + ((2 * km) ^ sw))         = f2bf(a  * val);
        *(unsigned short*)(A1 + r * 512 + ((192 + 2 * km) ^ sw))   = f2bf(cv * val);
    }
    __syncthreads();

    const unsigned short* Bf = (slot == 0) ? WsabF : WvabF;
    f32x4 acc1[6];
    #pragma unroll
    for (int nt = 0; nt < 6; ++nt) acc1[nt] = (f32x4)0.f;

    int arow = w * 16 + (lane & 15);
    int asw  = (arow & 7) << 4;
    #pragma unroll
    for (int ks = 0; ks < 6; ++ks) {
        int kb = ks * 64 + ((lane >> 4) << 4);
        bf16x8 af = *(const bf16x8*)(A1 + arow * 512 + (kb ^ asw));
        #pragma unroll
        for (int nt = 0; nt < 6; ++nt) {
            bf16x8 bfrag = *(const bf16x8*)(Bf + (size_t)(((nt * 6 + ks) * 64) + lane) * 8);
            acc1[nt] = __builtin_amdgcn_mfma_f32_16x16x32_bf16(af, bfrag, acc1[nt], 0, 0, 0);
        }
    }

    #pragma unroll
    for (int nt = 0; nt < 6; ++nt) {
        int ncol2 = (nt * 16 + (lane & 15)) * 2;
        #pragma unroll
        for (int r = 0; r < 4; ++r) {
            int row = w * 16 + ((lane >> 4) << 2) + r;
            *(unsigned short*)(A2 + row * 256 + (ncol2 ^ ((row & 7) << 4))) = f2bf(acc1[nt][r]);
        }
    }

    // RAW hazard fence: A2 written above (ds_write_b16), read below (ds_read_b128).
    // Rows are wave-private, but rely on explicit barrier (lgkmcnt(0)+s_barrier)
    // rather than compiler-inserted waits across casted LDS pointers — suspected
    // intermittent race caused R9's post-timing divergence.
    __syncthreads();

    int NT2 = (slot == 0) ? 4 : 2;
    const unsigned short* B2 = (slot == 0) ? Wl3sF : Wl3vF;
    f32x4 acc2[4];
    #pragma unroll
    for (int nt2 = 0; nt2 < 4; ++nt2) acc2[nt2] = (f32x4)0.f;

    #pragma unroll
    for (int ks = 0; ks < 3; ++ks) {
        int kb = ks * 64 + ((lane >> 4) << 4);
        bf16x8 a2 = *(const bf16x8*)(A2 + arow * 256 + (kb ^ ((arow & 7) << 4)));
        #pragma unroll
        for (int nt2 = 0; nt2 < 4; ++nt2) {
            if (nt2 < NT2) {
                bf16x8 b2 = *(const bf16x8*)(B2 + (size_t)(((nt2 * 3 + ks) * 64) + lane) * 8);
                acc2[nt2] = __builtin_amdgcn_mfma_f32_16x16x32_bf16(a2, b2, acc2[nt2], 0, 0, 0);
            }
        }
    }

    #pragma unroll
    for (int r = 0; r < 4; ++r) {
        int n = n0 + w * 16 + ((lane >> 4) << 2) + r;
        if (n >= NN) continue;
        float sv = C_X_ * sym[n];
        #pragma unroll
        for (int nt2 = 0; nt2 < 4; ++nt2) {
            if (nt2 < NT2) {
                int col = nt2 * 16 + (lane & 15);
                int d = (slot == 0) ? col : (64 + 3 * col + cc);
                out[(size_t)n * 160 + d] += sv * acc2[nt2][r];
            }
        }
    }
}

extern "C" void kernel_launch(void* const* d_in, const int* in_sizes, int n_in,
                              void* d_out, int out_size, void* d_ws, size_t ws_size,
                              hipStream_t stream) {
    const float* ni    = (const float*)d_in[0];
    const float* attr  = (const float*)d_in[1];
    const float* cattr = (const float*)d_in[2];
    const float* sym   = (const float*)d_in[3];
    const float* eattr = (const float*)d_in[4];
    const float* ele   = (const float*)d_in[5];
    const int*   esrc  = (const int*)d_in[6];
    const int*   edst  = (const int*)d_in[7];
    const float* Ws_sc_a = (const float*)d_in[8];
    const float* Wv_sc_a = (const float*)d_in[9];
    const float* Ws_sc_c = (const float*)d_in[10];
    const float* Wv_sc_c = (const float*)d_in[11];
    const float* Ws_l1_a = (const float*)d_in[12];
    const float* Wv_l1_a = (const float*)d_in[13];
    const float* Ws_l1_c = (const float*)d_in[14];
    const float* Wv_l1_c = (const float*)d_in[15];
    const float* Wfc1    = (const float*)d_in[16];
    const float* Wfc2    = (const float*)d_in[17];
    const float* Ws_l2_a = (const float*)d_in[18];
    const float* Wv_l2_a = (const float*)d_in[19];
    const float* Ws_l2_c = (const float*)d_in[20];
    const float* Wv_l2_c = (const float*)d_in[21];
    const float* Ws_l3   = (const float*)d_in[22];
    const float* Wv_l3   = (const float*)d_in[23];

    float* out = (float*)d_out;
    float* ws  = (float*)d_ws;
    float* x1  = ws;                          // NN*160
    float* agg = x1 + (size_t)NN * 160;       // NN*384
    float* W4s = agg + (size_t)NN * 384;      // 16384
    float* W4v = W4s + 16384;                 // 4096
    unsigned short* Wfragb = (unsigned short*)(W4v + 4096);  // 24576
    unsigned short* WsabF  = Wfragb + 24576;                 // 18432
    unsigned short* WvabF  = WsabF + 18432;                  // 18432
    unsigned short* Wl3sF  = WvabF + 18432;                  // 6144
    unsigned short* Wl3vF  = Wl3sF + 6144;                   // 3072
    unsigned short* wbuf   = Wl3vF + 3072;                   // NE*192
    int* cnt    = (int*)(wbuf + (size_t)NE * 192);           // NN
    int* start_ = cnt + NN;                                  // NN+1
    int* cursor = start_ + NN + 1;                           // NN
    int* sorted = cursor + NN;                               // NE

    size_t need = ((size_t)NN * 160 + (size_t)NN * 384 + 16384 + 4096) * 4
                + ((size_t)24576 + 18432 + 18432 + 6144 + 3072 + (size_t)NE * 192) * 2
                + ((size_t)NN * 3 + 1 + NE) * 4;
    if (ws_size < need) return;

    k_pack<<<(75776 + 255) / 256, 256, 0, stream>>>(
        Wfc2,
        Ws_sc_a, Ws_sc_c, Ws_l1_a, Ws_l1_c, W4s,
        Wv_sc_a, Wv_sc_c, Wv_l1_a, Wv_l1_c, W4v,
        Ws_l2_a, Ws_l2_c, Wv_l2_a, Wv_l2_c,
        Ws_l3, Wv_l3,
        Wfragb, WsabF, WvabF, Wl3sF, Wl3vF);

    k_node_prep<<<(NN * 160 + 255) / 256, 256, 0, stream>>>(
        ni, attr, cattr, W4s, W4v, x1, out);

    hipMemsetAsync(cnt, 0, (size_t)NN * sizeof(int), stream);
    k_hist<<<(NE + 255) / 256, 256, 0, stream>>>(edst, cnt);
    k_scan<<<1, 1024, 0, stream>>>(cnt, start_, cursor);
    k_scatter<<<(NE + 255) / 256, 256, 0, stream>>>(edst, cursor, sorted);
    k_edgew_mfma<<<NE / 64, 256, 0, stream>>>(ele, Wfc1, Wfragb, wbuf);
    k_gather<<<NN, 384, 0, stream>>>(start_, sorted, esrc, eattr, wbuf, x1, agg);

    k_l23<<<dim3((NN + 63) / 64, 4), 256, 0, stream>>>(
        agg, attr, cattr, sym, WsabF, WvabF, Wl3sF, Wl3vF, out);
}

// Round 11
// 563.990 us; speedup vs baseline: 4.0209x; 1.1829x over previous
//
#include <hip/hip_runtime.h>
#include <math.h>

#define NN 25000
#define NE 400000

static constexpr float C_S_ = 0.3826834323650898f;   // sin(pi/8)
static constexpr float C_X_ = 0.9238795325112867f;   // cos(pi/8)
static constexpr float Q_   = 0.25f;                 // 1/sqrt(16)
static constexpr float Q_S3 = 0.25f * 0.5773502691896258f; // Q / sqrt(3)

typedef __attribute__((ext_vector_type(8))) short bf16x8;
typedef __attribute__((ext_vector_type(4))) float f32x4;

__device__ inline unsigned short f2bf(float f) {
    union { float f; unsigned u; } v; v.f = f;
    unsigned r = v.u + 0x7fffu + ((v.u >> 16) & 1u);   // RNE
    return (unsigned short)(r >> 16);
}
__device__ inline float bf2f(unsigned short s) {
    union { unsigned u; float f; } v; v.u = ((unsigned)s) << 16;
    return v.f;
}

// ---------------- K0: pack weights --------------------------------------------
__global__ void k_pack(const float* __restrict__ Wfc2,
                       const float* __restrict__ Wsa, const float* __restrict__ Wsc,
                       const float* __restrict__ W1sa, const float* __restrict__ W1sc, float* __restrict__ W4s,
                       const float* __restrict__ Wva, const float* __restrict__ Wvc,
                       const float* __restrict__ W1va, const float* __restrict__ W1vc, float* __restrict__ W4v,
                       const float* __restrict__ Wl2sa, const float* __restrict__ Wl2sc,
                       const float* __restrict__ Wl2va, const float* __restrict__ Wl2vc,
                       const float* __restrict__ Wl3s, const float* __restrict__ Wl3v,
                       unsigned short* __restrict__ Wfragb,
                       unsigned short* __restrict__ WsabF, unsigned short* __restrict__ WvabF,
                       unsigned short* __restrict__ Wl3sF, unsigned short* __restrict__ Wl3vF)
{
    int t = blockIdx.x * blockDim.x + threadIdx.x;
    if (t < 4096) {
        int k = t >> 6, d = t & 63;
        ((float4*)W4s)[k*64+d] = make_float4(Wsa[k*64+d], Wsc[k*64+d], W1sa[k*64+d], W1sc[k*64+d]);
        return;
    }
    t -= 4096;
    if (t < 1024) {
        int u = t >> 5, o = t & 31;
        ((float4*)W4v)[u*32+o] = make_float4(Wva[u*32+o], Wvc[u*32+o], W1va[u*32+o], W1vc[u*32+o]);
        return;
    }
    t -= 1024;
    if (t < 24576) {
        int i = t & 7, l = (t >> 3) & 63, ks = (t >> 9) & 3, nt = t >> 11;
        int k = ks * 32 + ((l >> 4) << 3) + i;
        int n = nt * 16 + (l & 15);
        Wfragb[t] = (k < 100) ? f2bf(Wfc2[k * 192 + n]) : (unsigned short)0;
        return;
    }
    t -= 24576;
    if (t < 18432) {
        int i = t & 7, l = (t >> 3) & 63, rem = t >> 9;
        int ks = rem % 6, nt = rem / 6;
        int k = ks * 32 + ((l >> 4) << 3) + i;
        int n = nt * 16 + (l & 15);
        WsabF[t] = f2bf(k < 96 ? Wl2sa[k * 96 + n] : Wl2sc[(k - 96) * 96 + n]);
        return;
    }
    t -= 18432;
    if (t < 18432) {
        int i = t & 7, l = (t >> 3) & 63, rem = t >> 9;
        int ks = rem % 6, nt = rem / 6;
        int k = ks * 32 + ((l >> 4) << 3) + i;
        int n = nt * 16 + (l & 15);
        WvabF[t] = f2bf(k < 96 ? Wl2va[k * 96 + n] : Wl2vc[(k - 96) * 96 + n]);
        return;
    }
    t -= 18432;
    if (t < 6144) {
        int i = t & 7, l = (t >> 3) & 63, rem = t >> 9;
        int ks = rem % 3, nt = rem / 3;
        int k = ks * 32 + ((l >> 4) << 3) + i;
        int n = nt * 16 + (l & 15);
        Wl3sF[t] = f2bf(Wl3s[k * 64 + n]);
        return;
    }
    t -= 6144;
    if (t < 3072) {
        int i = t & 7, l = (t >> 3) & 63, rem = t >> 9;
        int ks = rem % 3, nt = rem / 3;
        int k = ks * 32 + ((l >> 4) << 3) + i;
        int n = nt * 16 + (l & 15);
        Wl3vF[t] = f2bf(Wl3v[k * 32 + n]);
        return;
    }
}

// ---------------- K1: node prep (packed weights) ------------------------------
__global__ __launch_bounds__(256) void k_node_prep(
    const float* __restrict__ ni, const float* __restrict__ attr, const float* __restrict__ cattr,
    const float* __restrict__ W4s, const float* __restrict__ W4v,
    float* __restrict__ x1, float* __restrict__ out)
{
    int t = blockIdx.x * blockDim.x + threadIdx.x;
    if (t >= NN * 160) return;
    int n = t / 160, d = t - n * 160;
    float a = attr[n], c = cattr[n];
    const float* row = ni + (size_t)n * 160;
    float ssa = 0.f, ssc = 0.f, s1a = 0.f, s1c = 0.f;
    if (d < 64) {
        const float4* W = (const float4*)W4s;
        #pragma unroll
        for (int k = 0; k < 64; ++k) {
            float x = row[k];
            float4 w = W[k * 64 + d];
            ssa += x * w.x; ssc += x * w.y; s1a += x * w.z; s1c += x * w.w;
        }
    } else {
        int idx = d - 64;
        int o = idx / 3, cc = idx - o * 3;
        const float4* W = (const float4*)W4v;
        #pragma unroll
        for (int u = 0; u < 32; ++u) {
            float x = row[64 + u * 3 + cc];
            float4 w = W[u * 32 + o];
            ssa += x * w.x; ssc += x * w.y; s1a += x * w.z; s1c += x * w.w;
        }
    }
    x1[t]  = a * s1a + c * s1c;
    out[t] = C_S_ * (a * ssa + c * ssc);
}

// ---------------- sort: histogram ---------------------------------------------
__global__ __launch_bounds__(256) void k_hist(const int* __restrict__ edst, int* __restrict__ cnt) {
    int e = blockIdx.x * blockDim.x + threadIdx.x;
    if (e >= NE) return;
    atomicAdd(&cnt[edst[e]], 1);
}

// ---------------- sort: single-block exclusive scan over NN counts ------------
__global__ __launch_bounds__(1024) void k_scan(const int* __restrict__ cnt,
                                               int* __restrict__ start, int* __restrict__ cursor) {
    __shared__ int wsum[16];
    __shared__ int carry_s;
    int lane = threadIdx.x & 63, wid = threadIdx.x >> 6;
    if (threadIdx.x == 0) carry_s = 0;
    __syncthreads();
    for (int base = 0; base < NN; base += 1024) {
        int i = base + threadIdx.x;
        int v = (i < NN) ? cnt[i] : 0;
        int x = v;
        #pragma unroll
        for (int off = 1; off < 64; off <<= 1) {
            int y = __shfl_up(x, off, 64);
            if (lane >= off) x += y;
        }
        if (lane == 63) wsum[wid] = x;
        __syncthreads();
        if (wid == 0 && lane < 16) {
            int s = wsum[lane];
            #pragma unroll
            for (int off = 1; off < 16; off <<= 1) {
                int y = __shfl_up(s, off, 64);
                if (lane >= off) s += y;
            }
            wsum[lane] = s;
        }
        __syncthreads();
        int woff = (wid > 0) ? wsum[wid - 1] : 0;
        int excl = x - v + woff + carry_s;
        if (i < NN) { start[i] = excl; cursor[i] = excl; }
        __syncthreads();
        if (threadIdx.x == 1023) carry_s += wsum[15];
        __syncthreads();
    }
    if (threadIdx.x == 0) start[NN] = NE;
}

// ---------------- sort: scatter edge ids --------------------------------------
__global__ __launch_bounds__(256) void k_scatter(const int* __restrict__ edst,
                                                 int* __restrict__ cursor,
                                                 int* __restrict__ sorted) {
    int e = blockIdx.x * blockDim.x + threadIdx.x;
    if (e >= NE) return;
    int p = atomicAdd(&cursor[edst[e]], 1);
    sorted[p] = e;
}

// ---------------- K2a: MFMA edge-weight GEMM ----------------------------------
__global__ __launch_bounds__(256, 2) void k_edgew_mfma(
    const float* __restrict__ ele,
    const float* __restrict__ Wfc1, const unsigned short* __restrict__ Wfragb,
    unsigned short* __restrict__ wbuf)
{
    __shared__ float ele_s[640];
    __shared__ char  hA[64 * 256];      // [row=edge][128 bf16], byte ^= (row&7)<<4

    int tid  = threadIdx.x;
    int lane = tid & 63;
    int w    = tid >> 6;
    int e0   = blockIdx.x * 64;

    for (int idx = tid; idx < 640; idx += 256)
        ele_s[idx] = ele[(size_t)e0 * 10 + idx];
    __syncthreads();

    #pragma unroll 1
    for (int it = 0; it < 25; ++it) {
        int t2 = tid + it * 256;
        int e_loc = t2 & 63;
        int j = t2 >> 6;
        const float* elp = ele_s + e_loc * 10;
        float acc = 0.f;
        #pragma unroll
        for (int k = 0; k < 10; ++k) acc += elp[k] * Wfc1[k * 100 + j];
        float hv = acc / (1.f + __expf(-acc));
        int col2 = j * 2;
        *(unsigned short*)(hA + e_loc * 256 + (col2 ^ ((e_loc & 7) << 4))) = f2bf(hv);
    }
    for (int idx = tid; idx < 64 * 28; idx += 256) {
        int e_loc = idx / 28;
        int col2 = (100 + (idx - e_loc * 28)) * 2;
        *(unsigned short*)(hA + e_loc * 256 + (col2 ^ ((e_loc & 7) << 4))) = 0;
    }
    __syncthreads();

    const bf16x8* Wv = (const bf16x8*)Wfragb;
    bf16x8 bfr[3][4];
    #pragma unroll
    for (int nt2 = 0; nt2 < 3; ++nt2)
        #pragma unroll
        for (int ks = 0; ks < 4; ++ks)
            bfr[nt2][ks] = Wv[(((w * 3 + nt2) * 4) + ks) * 64 + lane];

    f32x4 acc[4][3];
    #pragma unroll
    for (int mt = 0; mt < 4; ++mt)
        #pragma unroll
        for (int nt2 = 0; nt2 < 3; ++nt2)
            acc[mt][nt2] = (f32x4)0.f;

    #pragma unroll
    for (int mt = 0; mt < 4; ++mt) {
        int row = mt * 16 + (lane & 15);
        #pragma unroll
        for (int ks = 0; ks < 4; ++ks) {
            int kb = ks * 64 + ((lane >> 4) << 4);
            bf16x8 a = *(const bf16x8*)(hA + row * 256 + (kb ^ ((row & 7) << 4)));
            #pragma unroll
            for (int nt2 = 0; nt2 < 3; ++nt2)
                acc[mt][nt2] = __builtin_amdgcn_mfma_f32_16x16x32_bf16(a, bfr[nt2][ks], acc[mt][nt2], 0, 0, 0);
        }
    }

    #pragma unroll
    for (int mt = 0; mt < 4; ++mt) {
        #pragma unroll
        for (int nt2 = 0; nt2 < 3; ++nt2) {
            int n = w * 48 + nt2 * 16 + (lane & 15);
            #pragma unroll
            for (int r = 0; r < 4; ++r) {
                int e = e0 + mt * 16 + ((lane >> 4) << 2) + r;
                wbuf[(size_t)e * 192 + n] = f2bf(acc[mt][nt2][r]);
            }
        }
    }
}

// ---------------- K2b: per-node gather, 8-deep explicit load batching ---------
// R10 showed VGPR=12 (compiler serialized loads). launch_bounds(384,4) caps
// VGPR at 128; explicit register arrays with static indices give 8 loads in
// flight on the sorted->esrc/eattr/wbuf->x1 chain.
__global__ __launch_bounds__(384, 4) void k_gather(
    const int* __restrict__ start, const int* __restrict__ sorted,
    const int* __restrict__ esrc, const float* __restrict__ eattr,
    const unsigned short* __restrict__ wbuf, const float* __restrict__ x1,
    float* __restrict__ agg)
{
    int n = blockIdx.x;
    int t = threadIdx.x;
    int s0 = start[n], s1 = start[n + 1];

    int widx, gidx, kind, csel = 0;
    float scale;
    if (t < 64)       { widx = t;                gidx = t;              kind = 0; scale = Q_;   }
    else if (t < 96)  { int o = t - 64;          widx = 160 + o; gidx = 64 + 3 * o; kind = 1; scale = Q_S3; }
    else if (t < 288) { int idx = t - 96; int u = idx / 3; csel = idx - 3 * u;
                        widx = 64 + u;           gidx = u;              kind = 2; scale = Q_;   }
    else              { int idx = t - 288; int o = idx / 3; int c = idx - 3 * o;
                        widx = 128 + o;          gidx = 64 + 3 * o + c; kind = 0; scale = Q_;   }

    float a0 = 0.f, a1 = 0.f;
    int i = s0;
    for (; i + 8 <= s1; i += 8) {
        int eb[8];
        #pragma unroll
        for (int q = 0; q < 8; ++q) eb[q] = sorted[i + q];
        int srcb[8]; float4 eab[8]; float wvb[8];
        #pragma unroll
        for (int q = 0; q < 8; ++q) {
            srcb[q] = esrc[eb[q]];
            eab[q]  = *(const float4*)(eattr + (size_t)eb[q] * 4);
            wvb[q]  = bf2f(wbuf[(size_t)eb[q] * 192 + widx]);
        }
        float g0[8], g1[8], g2[8];
        #pragma unroll
        for (int q = 0; q < 8; ++q) {
            const float* g = x1 + (size_t)srcb[q] * 160;
            g0[q] = g[gidx];
            if (kind == 1) { g1[q] = g[gidx + 1]; g2[q] = g[gidx + 2]; }
        }
        #pragma unroll
        for (int q = 0; q < 8; ++q) {
            float* dst = (q & 1) ? &a1 : &a0;
            if (kind == 0)      *dst += wvb[q] * g0[q] * eab[q].x;
            else if (kind == 1) *dst += wvb[q] * (g0[q] * eab[q].y + g1[q] * eab[q].z + g2[q] * eab[q].w);
            else {
                float evc = (csel == 0) ? eab[q].y : ((csel == 1) ? eab[q].z : eab[q].w);
                *dst += wvb[q] * g0[q] * evc;
            }
        }
    }
    for (; i < s1; ++i) {
        int e = sorted[i];
        int src = esrc[e];
        float4 ea = *(const float4*)(eattr + (size_t)e * 4);
        const float* g = x1 + (size_t)src * 160;
        float wv = bf2f(wbuf[(size_t)e * 192 + widx]);
        if (kind == 0)      a0 += wv * g[gidx] * ea.x;
        else if (kind == 1) a0 += wv * (g[gidx] * ea.y + g[gidx + 1] * ea.z + g[gidx + 2] * ea.w);
        else {
            float evc = (csel == 0) ? ea.y : ((csel == 1) ? ea.z : ea.w);
            a0 += wv * g[gidx] * evc;
        }
    }

    agg[(size_t)n * 384 + t] = (a0 + a1) * scale;
}

// ---------------- K3: fused l2+l3 double-MFMA ---------------------------------
__global__ __launch_bounds__(256, 2) void k_l23(
    const float* __restrict__ agg, const float* __restrict__ attr,
    const float* __restrict__ cattr, const float* __restrict__ sym,
    const unsigned short* __restrict__ WsabF, const unsigned short* __restrict__ WvabF,
    const unsigned short* __restrict__ Wl3sF, const unsigned short* __restrict__ Wl3vF,
    float* __restrict__ out)
{
    __shared__ char A1[64 * 512];   // rows padded to 512B so XOR swizzle stays in-row
    __shared__ char A2[64 * 256];

    int slot = blockIdx.y;
    int cc   = slot - 1;
    int n0   = blockIdx.x * 64;
    int tid  = threadIdx.x, lane = tid & 63, w = tid >> 6;

    for (int idx = tid; idx < 64 * 96; idx += 256) {
        int r = idx / 96, km = idx - r * 96;
        int n = n0 + r;
        float a = 0.f, cv = 0.f, val = 0.f;
        if (n < NN) {
            a = attr[n]; cv = cattr[n];
            int src = (slot == 0) ? km : (96 + 3 * km + cc);
            val = agg[(size_t)n * 384 + src];
        }
        int sw = (r & 7) << 4;
        *(unsigned short*)(A1 + r * 512 + ((2 * km) ^ sw))         = f2bf(a  * val);
        *(unsigned short*)(A1 + r * 512 + ((192 + 2 * km) ^ sw))   = f2bf(cv * val);
    }
    __syncthreads();

    const unsigned short* Bf = (slot == 0) ? WsabF : WvabF;
    f32x4 acc1[6];
    #pragma unroll
    for (int nt = 0; nt < 6; ++nt) acc1[nt] = (f32x4)0.f;

    int arow = w * 16 + (lane & 15);
    int asw  = (arow & 7) << 4;
    #pragma unroll
    for (int ks = 0; ks < 6; ++ks) {
        int kb = ks * 64 + ((lane >> 4) << 4);
        bf16x8 af = *(const bf16x8*)(A1 + arow * 512 + (kb ^ asw));
        #pragma unroll
        for (int nt = 0; nt < 6; ++nt) {
            bf16x8 bfrag = *(const bf16x8*)(Bf + (size_t)(((nt * 6 + ks) * 64) + lane) * 8);
            acc1[nt] = __builtin_amdgcn_mfma_f32_16x16x32_bf16(af, bfrag, acc1[nt], 0, 0, 0);
        }
    }

    #pragma unroll
    for (int nt = 0; nt < 6; ++nt) {
        int ncol2 = (nt * 16 + (lane & 15)) * 2;
        #pragma unroll
        for (int r = 0; r < 4; ++r) {
            int row = w * 16 + ((lane >> 4) << 2) + r;
            *(unsigned short*)(A2 + row * 256 + (ncol2 ^ ((row & 7) << 4))) = f2bf(acc1[nt][r]);
        }
    }

    // RAW hazard fence (fixed R9's intermittent post-timing divergence)
    __syncthreads();

    int NT2 = (slot == 0) ? 4 : 2;
    const unsigned short* B2 = (slot == 0) ? Wl3sF : Wl3vF;
    f32x4 acc2[4];
    #pragma unroll
    for (int nt2 = 0; nt2 < 4; ++nt2) acc2[nt2] = (f32x4)0.f;

    #pragma unroll
    for (int ks = 0; ks < 3; ++ks) {
        int kb = ks * 64 + ((lane >> 4) << 4);
        bf16x8 a2 = *(const bf16x8*)(A2 + arow * 256 + (kb ^ ((arow & 7) << 4)));
        #pragma unroll
        for (int nt2 = 0; nt2 < 4; ++nt2) {
            if (nt2 < NT2) {
                bf16x8 b2 = *(const bf16x8*)(B2 + (size_t)(((nt2 * 3 + ks) * 64) + lane) * 8);
                acc2[nt2] = __builtin_amdgcn_mfma_f32_16x16x32_bf16(a2, b2, acc2[nt2], 0, 0, 0);
            }
        }
    }

    #pragma unroll
    for (int r = 0; r < 4; ++r) {
        int n = n0 + w * 16 + ((lane >> 4) << 2) + r;
        if (n >= NN) continue;
        float sv = C_X_ * sym[n];
        #pragma unroll
        for (int nt2 = 0; nt2 < 4; ++nt2) {
            if (nt2 < NT2) {
                int col = nt2 * 16 + (lane & 15);
                int d = (slot == 0) ? col : (64 + 3 * col + cc);
                out[(size_t)n * 160 + d] += sv * acc2[nt2][r];
            }
        }
    }
}

extern "C" void kernel_launch(void* const* d_in, const int* in_sizes, int n_in,
                              void* d_out, int out_size, void* d_ws, size_t ws_size,
                              hipStream_t stream) {
    const float* ni    = (const float*)d_in[0];
    const float* attr  = (const float*)d_in[1];
    const float* cattr = (const float*)d_in[2];
    const float* sym   = (const float*)d_in[3];
    const float* eattr = (const float*)d_in[4];
    const float* ele   = (const float*)d_in[5];
    const int*   esrc  = (const int*)d_in[6];
    const int*   edst  = (const int*)d_in[7];
    const float* Ws_sc_a = (const float*)d_in[8];
    const float* Wv_sc_a = (const float*)d_in[9];
    const float* Ws_sc_c = (const float*)d_in[10];
    const float* Wv_sc_c = (const float*)d_in[11];
    const float* Ws_l1_a = (const float*)d_in[12];
    const float* Wv_l1_a = (const float*)d_in[13];
    const float* Ws_l1_c = (const float*)d_in[14];
    const float* Wv_l1_c = (const float*)d_in[15];
    const float* Wfc1    = (const float*)d_in[16];
    const float* Wfc2    = (const float*)d_in[17];
    const float* Ws_l2_a = (const float*)d_in[18];
    const float* Wv_l2_a = (const float*)d_in[19];
    const float* Ws_l2_c = (const float*)d_in[20];
    const float* Wv_l2_c = (const float*)d_in[21];
    const float* Ws_l3   = (const float*)d_in[22];
    const float* Wv_l3   = (const float*)d_in[23];

    float* out = (float*)d_out;
    float* ws  = (float*)d_ws;
    float* x1  = ws;                          // NN*160
    float* agg = x1 + (size_t)NN * 160;       // NN*384
    float* W4s = agg + (size_t)NN * 384;      // 16384
    float* W4v = W4s + 16384;                 // 4096
    unsigned short* Wfragb = (unsigned short*)(W4v + 4096);  // 24576
    unsigned short* WsabF  = Wfragb + 24576;                 // 18432
    unsigned short* WvabF  = WsabF + 18432;                  // 18432
    unsigned short* Wl3sF  = WvabF + 18432;                  // 6144
    unsigned short* Wl3vF  = Wl3sF + 6144;                   // 3072
    unsigned short* wbuf   = Wl3vF + 3072;                   // NE*192
    int* cnt    = (int*)(wbuf + (size_t)NE * 192);           // NN
    int* start_ = cnt + NN;                                  // NN+1
    int* cursor = start_ + NN + 1;                           // NN
    int* sorted = cursor + NN;                               // NE

    size_t need = ((size_t)NN * 160 + (size_t)NN * 384 + 16384 + 4096) * 4
                + ((size_t)24576 + 18432 + 18432 + 6144 + 3072 + (size_t)NE * 192) * 2
                + ((size_t)NN * 3 + 1 + NE) * 4;
    if (ws_size < need) return;

    k_pack<<<(75776 + 255) / 256, 256, 0, stream>>>(
        Wfc2,
        Ws_sc_a, Ws_sc_c, Ws_l1_a, Ws_l1_c, W4s,
        Wv_sc_a, Wv_sc_c, Wv_l1_a, Wv_l1_c, W4v,
        Ws_l2_a, Ws_l2_c, Wv_l2_a, Wv_l2_c,
        Ws_l3, Wv_l3,
        Wfragb, WsabF, WvabF, Wl3sF, Wl3vF);

    k_node_prep<<<(NN * 160 + 255) / 256, 256, 0, stream>>>(
        ni, attr, cattr, W4s, W4v, x1, out);

    hipMemsetAsync(cnt, 0, (size_t)NN * sizeof(int), stream);
    k_hist<<<(NE + 255) / 256, 256, 0, stream>>>(edst, cnt);
    k_scan<<<1, 1024, 0, stream>>>(cnt, start_, cursor);
    k_scatter<<<(NE + 255) / 256, 256, 0, stream>>>(edst, cursor, sorted);
    k_edgew_mfma<<<NE / 64, 256, 0, stream>>>(ele, Wfc1, Wfragb, wbuf);
    k_gather<<<NN, 384, 0, stream>>>(start_, sorted, esrc, eattr, wbuf, x1, agg);

    k_l23<<<dim3((NN + 63) / 64, 4), 256, 0, stream>>>(
        agg, attr, cattr, sym, WsabF, WvabF, Wl3sF, Wl3vF, out);
}